// Round 5
// baseline (501.822 us; speedup 1.0000x reference)
//
#include <hip/hip_runtime.h>

// ---------------------------------------------------------------------------
// MultiHeadAttention: B=4, S=2048, D=1024, H=16, Dh=64. FP32 I/O.
// cvt-all-to-bf16 (+mask->bias table) -> merged QKV GEMM -> flash attention
// (fixed-max softmax; bias from global table as MFMA C-init; 64-key tiles,
// K/V double-buffered with V staged one tile late; PV DEFERRED one tile so
// its MFMAs overlap the exp2 chain of the next tile; XCD-sharded (b,h)) ->
// out GEMM (f32 out).
// ---------------------------------------------------------------------------

typedef __bf16 bf16x8 __attribute__((ext_vector_type(8)));
typedef __bf16 bf16x4 __attribute__((ext_vector_type(4)));
typedef float  f32x4  __attribute__((ext_vector_type(4)));

#define LOG2E 1.44269504088896340736f
#define SCALE_Q (0.125f * LOG2E)      // 1/sqrt(64) * log2(e), folded into Q
#define MBIAS_L2 (-1.44269504e9f)     // -1e9 * log2(e)
#define MFMA16(a, b, c) __builtin_amdgcn_mfma_f32_16x16x32_bf16(a, b, c, 0, 0, 0)

__device__ inline unsigned short f2bf(float f) {  // RNE f32 -> bf16 bits
  unsigned int u = __float_as_uint(f);
  u = u + 0x7FFF + ((u >> 16) & 1);
  return (unsigned short)(u >> 16);
}
__device__ inline void gload16(const void* g, void* l) {  // 16B global->LDS DMA
  __builtin_amdgcn_global_load_lds(
      (const __attribute__((address_space(1))) void*)g,
      (__attribute__((address_space(3))) void*)l, 16, 0, 0);
}
__device__ inline bf16x8 cvt8(const float* p) {  // 8 f32 -> bf16x8
  float4 a = *(const float4*)p, b = *(const float4*)(p + 4);
  bf16x8 v;
  v[0] = (__bf16)a.x; v[1] = (__bf16)a.y; v[2] = (__bf16)a.z; v[3] = (__bf16)a.w;
  v[4] = (__bf16)b.x; v[5] = (__bf16)b.y; v[6] = (__bf16)b.z; v[7] = (__bf16)b.w;
  return v;
}

// ---------------------------------------------------------------------------
// cvt_all: f32 -> bf16, 7 jobs (q,k,v,Wq,Wk,Wv,Wo) + job 7: mask int ->
// f32 bias table (0 / -1e9*log2e). grid (4096, 8), 256 thr.
// ---------------------------------------------------------------------------
struct CvtJob { const float* s; unsigned short* d; int n8; };
struct CvtJobs { CvtJob j[8]; };
__global__ void cvt_all(CvtJobs J) {
  CvtJob jb = J.j[blockIdx.y];
  int i = blockIdx.x * 256 + threadIdx.x;
  if (blockIdx.y == 7) {  // mask -> bias (8192 ints, int4/thread)
    if (i < jb.n8) {
      int4 m = ((const int4*)jb.s)[i];
      float4 o;
      o.x = m.x ? 0.f : MBIAS_L2;
      o.y = m.y ? 0.f : MBIAS_L2;
      o.z = m.z ? 0.f : MBIAS_L2;
      o.w = m.w ? 0.f : MBIAS_L2;
      ((float4*)jb.d)[i] = o;
    }
    return;
  }
  if (i < jb.n8) *(bf16x8*)(jb.d + (size_t)i * 8) = cvt8(jb.s + (size_t)i * 8);
}

// ---------------------------------------------------------------------------
// gemm_qkv: merged Q/K/V projections, one dispatch, grid (8, 64, 3).
// z in {0:Q, 1:K} swapped orientation (token-packed col-major stores);
// z==2 (V) normal orientation, writes Vt[(b*16+h)*64+d][s] directly.
// ---------------------------------------------------------------------------
struct ProjJob { const unsigned short* A; const unsigned short* W;
                 const float* bias; unsigned short* out; float scale; };
struct ProjJobs { ProjJob j[3]; };

__global__ __launch_bounds__(256, 2) void gemm_qkv(ProjJobs J) {
  __shared__ __align__(16) unsigned short Al[128 * 32];
  __shared__ __align__(16) unsigned short Wl[128 * 32];
  const int z = blockIdx.z;
  const ProjJob jb = J.j[z];
  const int tid = threadIdx.x, lane = tid & 63, w = tid >> 6;
  const int lid = lane & 15, lg = lane >> 4;
  const int c0 = blockIdx.x * 128, t0 = blockIdx.y * 128;
  const int wm = (w & 1) * 64, wn = (w >> 1) * 64;
  const unsigned short* Ml = (z == 2) ? Al : Wl;
  const unsigned short* Nl = (z == 2) ? Wl : Al;

  f32x4 acc[4][4];
#pragma unroll
  for (int i = 0; i < 4; i++)
#pragma unroll
    for (int j = 0; j < 4; j++) acc[i][j] = (f32x4){0.f, 0.f, 0.f, 0.f};

  for (int kt = 0; kt < 1024; kt += 32) {
    __syncthreads();
#pragma unroll
    for (int i = 0; i < 2; i++) {
      int c = i * 256 + tid, r = c >> 2, ko = (c & 3) * 8;
      gload16(jb.A + (size_t)(t0 + r) * 1024 + kt + ko, &Al[c * 8]);
      gload16(jb.W + (size_t)(c0 + r) * 1024 + kt + ko, &Wl[c * 8]);
    }
    __syncthreads();
    bf16x8 mf[4], nf[4];
#pragma unroll
    for (int mi = 0; mi < 4; mi++)
      mf[mi] = *(const bf16x8*)(&Ml[(wm + mi * 16 + lid) * 32 + lg * 8]);
#pragma unroll
    for (int ni = 0; ni < 4; ni++)
      nf[ni] = *(const bf16x8*)(&Nl[(wn + ni * 16 + lid) * 32 + lg * 8]);
#pragma unroll
    for (int mi = 0; mi < 4; mi++)
#pragma unroll
      for (int ni = 0; ni < 4; ni++)
        acc[mi][ni] = MFMA16(mf[mi], nf[ni], acc[mi][ni]);
  }

  if (z < 2) {
    const float scale = jb.scale;
#pragma unroll
    for (int mi = 0; mi < 4; mi++) {
      int colb = c0 + wm + mi * 16 + lg * 4;
      float4 b4 = *(const float4*)(&jb.bias[colb]);
#pragma unroll
      for (int ni = 0; ni < 4; ni++) {
        int token = t0 + wn + ni * 16 + lid;
        ushort4 st;
        st.x = f2bf((acc[mi][ni][0] + b4.x) * scale);
        st.y = f2bf((acc[mi][ni][1] + b4.y) * scale);
        st.z = f2bf((acc[mi][ni][2] + b4.z) * scale);
        st.w = f2bf((acc[mi][ni][3] + b4.w) * scale);
        *(ushort4*)(&jb.out[(size_t)token * 1024 + colb]) = st;
      }
    }
  } else {
    const int b = t0 >> 11;
#pragma unroll
    for (int ni = 0; ni < 4; ni++) {
      int col = c0 + wn + ni * 16 + lid;
      int h = col >> 6, d = col & 63;
      float bv = jb.bias[col];
#pragma unroll
      for (int mi = 0; mi < 4; mi++) {
        int s = (t0 & 2047) + wm + mi * 16 + lg * 4;
        ushort4 st;
        st.x = f2bf(acc[mi][ni][0] + bv);
        st.y = f2bf(acc[mi][ni][1] + bv);
        st.z = f2bf(acc[mi][ni][2] + bv);
        st.w = f2bf(acc[mi][ni][3] + bv);
        *(ushort4*)(&jb.out[(size_t)((b * 16 + h) * 64 + d) * 2048 + s]) = st;
      }
    }
  }
}

// ---------------------------------------------------------------------------
// gemm_o: f32 C[token][col] = A_bf16 @ W_bf16^T + bias. grid (8, 64).
// ---------------------------------------------------------------------------
__global__ __launch_bounds__(256, 2) void gemm_o(
    const unsigned short* __restrict__ A, const unsigned short* __restrict__ W,
    const float* __restrict__ bias, float* __restrict__ C) {
  __shared__ __align__(16) unsigned short Al[128 * 32];
  __shared__ __align__(16) unsigned short Wl[128 * 32];
  const int tid = threadIdx.x, lane = tid & 63, w = tid >> 6;
  const int lid = lane & 15, lg = lane >> 4;
  const int c0 = blockIdx.x * 128, t0 = blockIdx.y * 128;
  const int wc = (w & 1) * 64, wt = (w >> 1) * 64;
  f32x4 acc[4][4];
#pragma unroll
  for (int i = 0; i < 4; i++)
#pragma unroll
    for (int j = 0; j < 4; j++) acc[i][j] = (f32x4){0.f, 0.f, 0.f, 0.f};

  for (int kt = 0; kt < 1024; kt += 32) {
    __syncthreads();
#pragma unroll
    for (int i = 0; i < 2; i++) {
      int c = i * 256 + tid, r = c >> 2, ko = (c & 3) * 8;
      gload16(A + (size_t)(t0 + r) * 1024 + kt + ko, &Al[c * 8]);
      gload16(W + (size_t)(c0 + r) * 1024 + kt + ko, &Wl[c * 8]);
    }
    __syncthreads();
    bf16x8 aw[4], bt[4];
#pragma unroll
    for (int mi = 0; mi < 4; mi++)
      aw[mi] = *(const bf16x8*)(&Wl[(wc + mi * 16 + lid) * 32 + lg * 8]);
#pragma unroll
    for (int ni = 0; ni < 4; ni++)
      bt[ni] = *(const bf16x8*)(&Al[(wt + ni * 16 + lid) * 32 + lg * 8]);
#pragma unroll
    for (int mi = 0; mi < 4; mi++)
#pragma unroll
      for (int ni = 0; ni < 4; ni++)
        acc[mi][ni] = MFMA16(aw[mi], bt[ni], acc[mi][ni]);
  }
#pragma unroll
  for (int mi = 0; mi < 4; mi++) {
    int colb = c0 + wc + mi * 16 + lg * 4;
    float4 b4 = *(const float4*)(&bias[colb]);
#pragma unroll
    for (int ni = 0; ni < 4; ni++) {
      int token = t0 + wt + ni * 16 + lid;
      float4 st;
      st.x = acc[mi][ni][0] + b4.x;
      st.y = acc[mi][ni][1] + b4.y;
      st.z = acc[mi][ni][2] + b4.z;
      st.w = acc[mi][ni][3] + b4.w;
      *(float4*)(&C[(size_t)token * 1024 + colb]) = st;
    }
  }
}

// ---------------------------------------------------------------------------
// Flash attention v8: deferred-PV software pipeline.
//
// Counters R2: MfmaUtil 35, VALUBusy 39, ~26% no-issue; occupancy capacity
// (4 blk/CU) didn't help -> per-wave serial chain QK->exp->PV + lockstep
// barrier is the stall. Changes:
//  * PV deferred one tile: iteration i = {stage_K(i+1), stage_V(i), QK(i),
//    PV(i-1) [INDEPENDENT 20 MFMA], exp(i), barrier}. In-order issue sends
//    QK+PV MFMAs back-to-back; exp(i)'s ~300 VALU cycles overlap PV's pipe
//    drain. V staged one tile LATE so 2 buffers suffice: V(i) staged iter i,
//    read iter i+1 (PV(i)), overwritten iter i+2.
//  * Mask bias from precomputed global f32 table (cvt_all job 7): kills
//    mball LDS (8KB) + its per-tile LDS reads. LDS 32KB.
//  * XCD shard: all 16 q-blocks of one (b,h) on one XCD -> K/V (512KB)
//    fetched once into that L2 (FETCH_SIZE ~139MB -> ~60MB expected).
// grid (16, 64), 256 thr. LDS 32KB. launch_bounds (256,4): VGPR <= 128.
// ---------------------------------------------------------------------------
__global__ __launch_bounds__(256, 4) void attn(
    const unsigned short* __restrict__ Qp,   // (B*S, 1024), pre-scaled
    const unsigned short* __restrict__ Kp,   // (B*S, 1024)
    const unsigned short* __restrict__ Vt,   // (B*H, 64, 2048)
    const float* __restrict__ mbias,         // (B, 2048) f32 bias table
    unsigned short* __restrict__ ctx) {      // (B*S, 1024)
  __shared__ __align__(16) unsigned short Klds[2][64 * 64];  // [key][d], XOR-swz
  __shared__ __align__(16) unsigned short Vlds[2][64 * 64];  // [d][key], XOR-swz

  const int tid = threadIdx.x, lane = tid & 63, w = tid >> 6;
  const int lid = lane & 15, lg = lane >> 4;
  // XCD shard: wg -> (xcd, idx); bh = xcd*8 + idx/16 so one (b,h)'s 16
  // q-blocks stay on one XCD's L2. Bijective over 1024 = 8*8*16.
  const int wg = blockIdx.x + (int)(gridDim.x) * blockIdx.y;
  const int xcd = wg & 7, idx = wg >> 3;
  const int bh = (xcd << 3) | (idx >> 4);
  const int q0 = (idx & 15) * 128;
  const int b = bh >> 4, h = bh & 15;
  const int wq = w * 32;
  const int x7 = lid & 7;  // XOR swizzle key (row&7 == lid&7 for all reads)

  const unsigned short* Kg = Kp + (size_t)(b * 2048) * 1024 + h * 64;
  const unsigned short* Vg = Vt + (size_t)bh * 64 * 2048;
  const float* mg = mbias + b * 2048;

  // Q fragments (B-operand of S^T): lane holds Q[q=nt*16+lid][d=ks*32+lg*8..]
  bf16x8 qf[2][2];
#pragma unroll
  for (int nt = 0; nt < 2; nt++)
#pragma unroll
    for (int ks = 0; ks < 2; ks++) {
      int qrow = b * 2048 + q0 + wq + nt * 16 + lid;
      qf[nt][ks] = *(const bf16x8*)(Qp + (size_t)qrow * 1024 + h * 64 + ks * 32 + lg * 8);
    }

  f32x4 Ot[4][2];  // O^T[d=dt*16+lg*4+r][q=qt*16+lid]
#pragma unroll
  for (int dt = 0; dt < 4; dt++)
#pragma unroll
    for (int qt = 0; qt < 2; qt++) Ot[dt][qt] = (f32x4){0.f, 0.f, 0.f, 0.f};
  f32x4 acc_l[2] = {(f32x4){0.f, 0.f, 0.f, 0.f}, (f32x4){0.f, 0.f, 0.f, 0.f}};
  bf16x8 ones8;
#pragma unroll
  for (int i = 0; i < 8; i++) ones8[i] = (__bf16)1.0f;

  auto stage_K = [&](unsigned short* Kl, int k0) {
#pragma unroll
    for (int i = 0; i < 2; i++) {
      int c = i * 256 + tid, r = c >> 3, gsw = (c & 7) ^ (r & 7);
      gload16(Kg + (size_t)(k0 + r) * 1024 + gsw * 8, Kl + c * 8);
    }
  };
  auto stage_V = [&](unsigned short* Vl, int k0) {
#pragma unroll
    for (int i = 0; i < 2; i++) {
      int c = i * 256 + tid, d = c >> 3, gsw = (c & 7) ^ (d & 7);
      gload16(Vg + (size_t)d * 2048 + k0 + gsw * 8, Vl + c * 8);
    }
  };

  // QK^T of tile kt from Kl; C-init = mask bias loaded from global table.
  auto qk = [&](int kt, const unsigned short* Kl, f32x4 (&accS)[4][2]) {
    const float* mrow = mg + kt * 64;
#pragma unroll
    for (int mt = 0; mt < 4; mt++) {
      f32x4 mb4 = *(const f32x4*)(&mrow[mt * 16 + lg * 4]);
      accS[mt][0] = mb4;
      accS[mt][1] = mb4;
    }
    __builtin_amdgcn_s_setprio(1);
#pragma unroll
    for (int ks = 0; ks < 2; ks++) {
      int koff = ((ks * 4 + lg) ^ x7) * 8;  // swizzled granule within row
#pragma unroll
      for (int mt = 0; mt < 4; mt++) {
        bf16x8 a = *(const bf16x8*)(&Kl[(mt * 16 + lid) * 64 + koff]);
        accS[mt][0] = MFMA16(a, qf[0][ks], accS[mt][0]);
        accS[mt][1] = MFMA16(a, qf[1][ks], accS[mt][1]);
      }
    }
    __builtin_amdgcn_s_setprio(0);
  };

  // PV + ones-rowsum for the PREVIOUS tile (independent of current QK/exp).
  auto pv = [&](bf16x8 (&pb)[2][2], const unsigned short* Vl) {
    __builtin_amdgcn_s_setprio(1);
#pragma unroll
    for (int c = 0; c < 2; c++)
#pragma unroll
      for (int qt = 0; qt < 2; qt++)
        acc_l[qt] = MFMA16(ones8, pb[c][qt], acc_l[qt]);
    // O^T += V^T . P^T; phys k=lg*8+j <-> key 32*c+16*(j>=4)+lg*4+(j&3)
#pragma unroll
    for (int c = 0; c < 2; c++) {
      int glo = ((4 * c + (lg >> 1)) ^ x7) * 8 + (lg & 1) * 4;
      int ghi = ((4 * c + 2 + (lg >> 1)) ^ x7) * 8 + (lg & 1) * 4;
#pragma unroll
      for (int dt = 0; dt < 4; dt++) {
        const unsigned short* vrow = &Vl[(dt * 16 + lid) * 64];
        bf16x4 lo = *(const bf16x4*)(&vrow[glo]);
        bf16x4 hi = *(const bf16x4*)(&vrow[ghi]);
        bf16x8 av = __builtin_shufflevector(lo, hi, 0, 1, 2, 3, 4, 5, 6, 7);
#pragma unroll
        for (int qt = 0; qt < 2; qt++)
          Ot[dt][qt] = MFMA16(av, pb[c][qt], Ot[dt][qt]);
      }
    }
    __builtin_amdgcn_s_setprio(0);
  };

  // fixed-max softmax: p = exp2(score); P packed into B-frags pb[c][qt]
  auto sm = [&](f32x4 (&accS)[4][2], bf16x8 (&pbCur)[2][2]) {
#pragma unroll
    for (int nt = 0; nt < 2; nt++)
#pragma unroll
      for (int mt = 0; mt < 4; mt++) {
        int half = (mt & 1) * 4;
#pragma unroll
        for (int r = 0; r < 4; r++) {
          float p = __builtin_amdgcn_exp2f(accS[mt][nt][r]);
          pbCur[mt >> 1][nt][half + r] = (__bf16)p;
        }
      }
  };

  bf16x8 pbA[2][2], pbB[2][2];

  // iteration kt (buffer kb = kt&1): stage_K(kt+1)->K[kb^1], stage_V(kt)->
  // V[kb]; QK(kt) from K[kb]; PV(kt-1) from V[kb^1] (landed at prev barrier);
  // exp(kt); barrier (lands both stages, retires this tile's LDS reads).
  auto body = [&](int kt, int kb, auto& pbPrev, auto& pbCur, int first, int last) {
    if (!last) stage_K(&Klds[kb ^ 1][0], (kt + 1) * 64);
    stage_V(&Vlds[kb][0], kt * 64);
    f32x4 accS[4][2];
    qk(kt, &Klds[kb][0], accS);
    if (!first) pv(pbPrev, &Vlds[kb ^ 1][0]);
    sm(accS, pbCur);
    __syncthreads();
  };

  stage_K(&Klds[0][0], 0);
  __syncthreads();  // drains vmcnt(0): K(0) ready

  body(0, 0, pbB, pbA, 1, 0);
  for (int kt = 1; kt < 31; kt += 2) {
    body(kt, 1, pbA, pbB, 0, 0);
    body(kt + 1, 0, pbB, pbA, 0, 0);
  }
  body(31, 1, pbA, pbB, 0, 1);
  pv(pbB, &Vlds[1][0]);  // PV(31): V(31) landed at the final barrier

  // epilogue: ctx[q][h*64+d] = O^T/l ; d packed x4 -> 8B stores
#pragma unroll
  for (int qt = 0; qt < 2; qt++) {
    float inv = 1.0f / acc_l[qt][0];
    int qrow = b * 2048 + q0 + wq + qt * 16 + lid;
#pragma unroll
    for (int dt = 0; dt < 4; dt++) {
      ushort4 st;
      st.x = f2bf(Ot[dt][qt][0] * inv);
      st.y = f2bf(Ot[dt][qt][1] * inv);
      st.z = f2bf(Ot[dt][qt][2] * inv);
      st.w = f2bf(Ot[dt][qt][3] * inv);
      *(ushort4*)(&ctx[(size_t)qrow * 1024 + h * 64 + dt * 16 + lg * 4]) = st;
    }
  }
}

// ---------------------------------------------------------------------------
extern "C" void kernel_launch(void* const* d_in, const int* in_sizes, int n_in,
                              void* d_out, int out_size, void* d_ws, size_t ws_size,
                              hipStream_t stream) {
  const float* q  = (const float*)d_in[0];
  const float* k  = (const float*)d_in[1];
  const float* v  = (const float*)d_in[2];
  const int*   mk = (const int*)d_in[3];
  const float* Wq = (const float*)d_in[4];
  const float* bq = (const float*)d_in[5];
  const float* Wk = (const float*)d_in[6];
  const float* bk = (const float*)d_in[7];
  const float* Wv = (const float*)d_in[8];
  const float* bv = (const float*)d_in[9];
  const float* Wo = (const float*)d_in[10];
  const float* bo = (const float*)d_in[11];

  const size_t NTOK = (size_t)8192 * 1024;   // elements per activation tensor
  const size_t NW = (size_t)1024 * 1024;     // elements per weight

  unsigned short* qb  = (unsigned short*)d_ws;
  unsigned short* kb  = qb + NTOK;
  unsigned short* vb  = kb + NTOK;
  unsigned short* Qp  = vb + NTOK;
  unsigned short* Kp  = Qp + NTOK;
  unsigned short* Vt  = Kp + NTOK;
  unsigned short* Wqb = Vt + NTOK;
  unsigned short* Wkb = Wqb + NW;
  unsigned short* Wvb = Wkb + NW;
  unsigned short* Wob = Wvb + NW;
  float*          mbg = (float*)(Wob + NW);  // (B,2048) f32 bias table, 32KB
  unsigned short* ctx = qb;  // qb dead after QKV projections

  CvtJobs J;
  J.j[0] = {q, qb, (int)(NTOK / 8)};
  J.j[1] = {k, kb, (int)(NTOK / 8)};
  J.j[2] = {v, vb, (int)(NTOK / 8)};
  J.j[3] = {Wq, Wqb, (int)(NW / 8)};
  J.j[4] = {Wk, Wkb, (int)(NW / 8)};
  J.j[5] = {Wv, Wvb, (int)(NW / 8)};
  J.j[6] = {Wo, Wob, (int)(NW / 8)};
  J.j[7] = {(const float*)mk, (unsigned short*)mbg, 2048};  // mask -> bias
  cvt_all<<<dim3(4096, 8), 256, 0, stream>>>(J);

  ProjJobs P;
  P.j[0] = {qb, Wqb, bq, Qp, SCALE_Q};
  P.j[1] = {kb, Wkb, bk, Kp, 1.0f};
  P.j[2] = {vb, Wvb, bv, Vt, 1.0f};
  gemm_qkv<<<dim3(8, 64, 3), 256, 0, stream>>>(P);

  attn<<<dim3(16, 64), 256, 0, stream>>>(Qp, Kp, Vt, mbg, ctx);
  gemm_o<<<dim3(8, 64), 256, 0, stream>>>(ctx, Wob, bo, (float*)d_out);
}

// Round 6
// 353.507 us; speedup vs baseline: 1.4196x; 1.4196x over previous
//
#include <hip/hip_runtime.h>

// ---------------------------------------------------------------------------
// MultiHeadAttention: B=4, S=2048, D=1024, H=16, Dh=64. FP32 I/O.
// cvt-all-to-bf16 (+mask->bias table) -> merged QKV GEMM -> flash attention
// (fixed-max softmax; bias from global table as MFMA C-init; 64-key tiles,
// K/V double-buffered; compute split by q-half so accS halves and qk/exp of
// opposite halves overlap; fits 128-reg class -> 4 waves/SIMD) ->
// out GEMM (f32 out).
// ---------------------------------------------------------------------------

typedef __bf16 bf16x8 __attribute__((ext_vector_type(8)));
typedef __bf16 bf16x4 __attribute__((ext_vector_type(4)));
typedef float  f32x4  __attribute__((ext_vector_type(4)));

#define LOG2E 1.44269504088896340736f
#define SCALE_Q (0.125f * LOG2E)      // 1/sqrt(64) * log2(e), folded into Q
#define MBIAS_L2 (-1.44269504e9f)     // -1e9 * log2(e)
#define MFMA16(a, b, c) __builtin_amdgcn_mfma_f32_16x16x32_bf16(a, b, c, 0, 0, 0)

__device__ inline unsigned short f2bf(float f) {  // RNE f32 -> bf16 bits
  unsigned int u = __float_as_uint(f);
  u = u + 0x7FFF + ((u >> 16) & 1);
  return (unsigned short)(u >> 16);
}
__device__ inline void gload16(const void* g, void* l) {  // 16B global->LDS DMA
  __builtin_amdgcn_global_load_lds(
      (const __attribute__((address_space(1))) void*)g,
      (__attribute__((address_space(3))) void*)l, 16, 0, 0);
}
__device__ inline bf16x8 cvt8(const float* p) {  // 8 f32 -> bf16x8
  float4 a = *(const float4*)p, b = *(const float4*)(p + 4);
  bf16x8 v;
  v[0] = (__bf16)a.x; v[1] = (__bf16)a.y; v[2] = (__bf16)a.z; v[3] = (__bf16)a.w;
  v[4] = (__bf16)b.x; v[5] = (__bf16)b.y; v[6] = (__bf16)b.z; v[7] = (__bf16)b.w;
  return v;
}

// ---------------------------------------------------------------------------
// cvt_all: f32 -> bf16, 7 jobs (q,k,v,Wq,Wk,Wv,Wo) + job 7: mask int ->
// f32 bias table (0 / -1e9*log2e). grid (4096, 8), 256 thr.
// ---------------------------------------------------------------------------
struct CvtJob { const float* s; unsigned short* d; int n8; };
struct CvtJobs { CvtJob j[8]; };
__global__ void cvt_all(CvtJobs J) {
  CvtJob jb = J.j[blockIdx.y];
  int i = blockIdx.x * 256 + threadIdx.x;
  if (blockIdx.y == 7) {  // mask -> bias (8192 ints, int4/thread)
    if (i < jb.n8) {
      int4 m = ((const int4*)jb.s)[i];
      float4 o;
      o.x = m.x ? 0.f : MBIAS_L2;
      o.y = m.y ? 0.f : MBIAS_L2;
      o.z = m.z ? 0.f : MBIAS_L2;
      o.w = m.w ? 0.f : MBIAS_L2;
      ((float4*)jb.d)[i] = o;
    }
    return;
  }
  if (i < jb.n8) *(bf16x8*)(jb.d + (size_t)i * 8) = cvt8(jb.s + (size_t)i * 8);
}

// ---------------------------------------------------------------------------
// gemm_qkv: merged Q/K/V projections, one dispatch, grid (8, 64, 3).
// z in {0:Q, 1:K} swapped orientation (token-packed col-major stores);
// z==2 (V) normal orientation, writes Vt[(b*16+h)*64+d][s] directly.
// ---------------------------------------------------------------------------
struct ProjJob { const unsigned short* A; const unsigned short* W;
                 const float* bias; unsigned short* out; float scale; };
struct ProjJobs { ProjJob j[3]; };

__global__ __launch_bounds__(256, 2) void gemm_qkv(ProjJobs J) {
  __shared__ __align__(16) unsigned short Al[128 * 32];
  __shared__ __align__(16) unsigned short Wl[128 * 32];
  const int z = blockIdx.z;
  const ProjJob jb = J.j[z];
  const int tid = threadIdx.x, lane = tid & 63, w = tid >> 6;
  const int lid = lane & 15, lg = lane >> 4;
  const int c0 = blockIdx.x * 128, t0 = blockIdx.y * 128;
  const int wm = (w & 1) * 64, wn = (w >> 1) * 64;
  const unsigned short* Ml = (z == 2) ? Al : Wl;
  const unsigned short* Nl = (z == 2) ? Wl : Al;

  f32x4 acc[4][4];
#pragma unroll
  for (int i = 0; i < 4; i++)
#pragma unroll
    for (int j = 0; j < 4; j++) acc[i][j] = (f32x4){0.f, 0.f, 0.f, 0.f};

  for (int kt = 0; kt < 1024; kt += 32) {
    __syncthreads();
#pragma unroll
    for (int i = 0; i < 2; i++) {
      int c = i * 256 + tid, r = c >> 2, ko = (c & 3) * 8;
      gload16(jb.A + (size_t)(t0 + r) * 1024 + kt + ko, &Al[c * 8]);
      gload16(jb.W + (size_t)(c0 + r) * 1024 + kt + ko, &Wl[c * 8]);
    }
    __syncthreads();
    bf16x8 mf[4], nf[4];
#pragma unroll
    for (int mi = 0; mi < 4; mi++)
      mf[mi] = *(const bf16x8*)(&Ml[(wm + mi * 16 + lid) * 32 + lg * 8]);
#pragma unroll
    for (int ni = 0; ni < 4; ni++)
      nf[ni] = *(const bf16x8*)(&Nl[(wn + ni * 16 + lid) * 32 + lg * 8]);
#pragma unroll
    for (int mi = 0; mi < 4; mi++)
#pragma unroll
      for (int ni = 0; ni < 4; ni++)
        acc[mi][ni] = MFMA16(mf[mi], nf[ni], acc[mi][ni]);
  }

  if (z < 2) {
    const float scale = jb.scale;
#pragma unroll
    for (int mi = 0; mi < 4; mi++) {
      int colb = c0 + wm + mi * 16 + lg * 4;
      float4 b4 = *(const float4*)(&jb.bias[colb]);
#pragma unroll
      for (int ni = 0; ni < 4; ni++) {
        int token = t0 + wn + ni * 16 + lid;
        ushort4 st;
        st.x = f2bf((acc[mi][ni][0] + b4.x) * scale);
        st.y = f2bf((acc[mi][ni][1] + b4.y) * scale);
        st.z = f2bf((acc[mi][ni][2] + b4.z) * scale);
        st.w = f2bf((acc[mi][ni][3] + b4.w) * scale);
        *(ushort4*)(&jb.out[(size_t)token * 1024 + colb]) = st;
      }
    }
  } else {
    const int b = t0 >> 11;
#pragma unroll
    for (int ni = 0; ni < 4; ni++) {
      int col = c0 + wn + ni * 16 + lid;
      int h = col >> 6, d = col & 63;
      float bv = jb.bias[col];
#pragma unroll
      for (int mi = 0; mi < 4; mi++) {
        int s = (t0 & 2047) + wm + mi * 16 + lg * 4;
        ushort4 st;
        st.x = f2bf(acc[mi][ni][0] + bv);
        st.y = f2bf(acc[mi][ni][1] + bv);
        st.z = f2bf(acc[mi][ni][2] + bv);
        st.w = f2bf(acc[mi][ni][3] + bv);
        *(ushort4*)(&jb.out[(size_t)((b * 16 + h) * 64 + d) * 2048 + s]) = st;
      }
    }
  }
}

// ---------------------------------------------------------------------------
// gemm_o: f32 C[token][col] = A_bf16 @ W_bf16^T + bias. grid (8, 64).
// ---------------------------------------------------------------------------
__global__ __launch_bounds__(256, 2) void gemm_o(
    const unsigned short* __restrict__ A, const unsigned short* __restrict__ W,
    const float* __restrict__ bias, float* __restrict__ C) {
  __shared__ __align__(16) unsigned short Al[128 * 32];
  __shared__ __align__(16) unsigned short Wl[128 * 32];
  const int tid = threadIdx.x, lane = tid & 63, w = tid >> 6;
  const int lid = lane & 15, lg = lane >> 4;
  const int c0 = blockIdx.x * 128, t0 = blockIdx.y * 128;
  const int wc = (w & 1) * 64, wt = (w >> 1) * 64;
  f32x4 acc[4][4];
#pragma unroll
  for (int i = 0; i < 4; i++)
#pragma unroll
    for (int j = 0; j < 4; j++) acc[i][j] = (f32x4){0.f, 0.f, 0.f, 0.f};

  for (int kt = 0; kt < 1024; kt += 32) {
    __syncthreads();
#pragma unroll
    for (int i = 0; i < 2; i++) {
      int c = i * 256 + tid, r = c >> 2, ko = (c & 3) * 8;
      gload16(A + (size_t)(t0 + r) * 1024 + kt + ko, &Al[c * 8]);
      gload16(W + (size_t)(c0 + r) * 1024 + kt + ko, &Wl[c * 8]);
    }
    __syncthreads();
    bf16x8 aw[4], bt[4];
#pragma unroll
    for (int mi = 0; mi < 4; mi++)
      aw[mi] = *(const bf16x8*)(&Wl[(wc + mi * 16 + lid) * 32 + lg * 8]);
#pragma unroll
    for (int ni = 0; ni < 4; ni++)
      bt[ni] = *(const bf16x8*)(&Al[(wt + ni * 16 + lid) * 32 + lg * 8]);
#pragma unroll
    for (int mi = 0; mi < 4; mi++)
#pragma unroll
      for (int ni = 0; ni < 4; ni++)
        acc[mi][ni] = MFMA16(aw[mi], bt[ni], acc[mi][ni]);
  }
#pragma unroll
  for (int mi = 0; mi < 4; mi++) {
    int colb = c0 + wc + mi * 16 + lg * 4;
    float4 b4 = *(const float4*)(&bias[colb]);
#pragma unroll
    for (int ni = 0; ni < 4; ni++) {
      int token = t0 + wt + ni * 16 + lid;
      float4 st;
      st.x = acc[mi][ni][0] + b4.x;
      st.y = acc[mi][ni][1] + b4.y;
      st.z = acc[mi][ni][2] + b4.z;
      st.w = acc[mi][ni][3] + b4.w;
      *(float4*)(&C[(size_t)token * 1024 + colb]) = st;
    }
  }
}

// ---------------------------------------------------------------------------
// Flash attention v9: q-half-split compute, 128-reg class.
//
// R5 post-mortem: v8's deferred-PV needed ~150 combined VGPR+AGPR; with
// launch_bounds(256,4) (128-reg cap) it spilled (WRITE_SIZE 16->556MB,
// dur 92->235us). Occupancy classes: <=64 regs -> 8 waves/SIMD, <=128 -> 4,
// <=256 -> 2; R1/R2 variants sat at ~136-160 combined -> 2/SIMD, which is
// why occupancy never passed ~24%. v9 restructures to fit <=128:
//  * compute split by q-half: qk(qt0)->sm(qt0)->qk(qt1)->sm(qt1)->pv(joint).
//    accS halves to 16 regs (one qt live at a time); qk(qt1) MFMAs overlap
//    sm(qt0) exp chain, pv qt0-half overlaps sm(qt1) - the deferred-PV
//    overlap without its register bloat. Peak ~115 combined.
//  * 64-key tiles, K+V double-buffered, 1 barrier/tile (R2's proven loop).
//  * mask bias from global f32 table (L2-resident 32KB); LDS 32KB.
//  * XCD shard: all 16 q-blocks of one (b,h) on one XCD's L2.
// grid (16, 64), 256 thr. Tripwire: WRITE_SIZE must be ~16MB (no spill).
// ---------------------------------------------------------------------------
__global__ __launch_bounds__(256, 4) void attn(
    const unsigned short* __restrict__ Qp,   // (B*S, 1024), pre-scaled
    const unsigned short* __restrict__ Kp,   // (B*S, 1024)
    const unsigned short* __restrict__ Vt,   // (B*H, 64, 2048)
    const float* __restrict__ mbias,         // (B, 2048) f32 bias table
    unsigned short* __restrict__ ctx) {      // (B*S, 1024)
  __shared__ __align__(16) unsigned short Klds[2][64 * 64];  // [key][d], XOR-swz
  __shared__ __align__(16) unsigned short Vlds[2][64 * 64];  // [d][key], XOR-swz

  const int tid = threadIdx.x, lane = tid & 63, w = tid >> 6;
  const int lid = lane & 15, lg = lane >> 4;
  // XCD shard: wg -> (xcd, idx); bh = xcd*8 + idx/16 so one (b,h)'s 16
  // q-blocks stay on one XCD's L2. Bijective over 1024 = 8*8*16.
  const int wg = blockIdx.x + (int)(gridDim.x) * blockIdx.y;
  const int xcd = wg & 7, idx = wg >> 3;
  const int bh = (xcd << 3) | (idx >> 4);
  const int q0 = (idx & 15) * 128;
  const int b = bh >> 4, h = bh & 15;
  const int wq = w * 32;
  const int x7 = lid & 7;  // XOR swizzle key (row&7 == lid&7 for all reads)

  const unsigned short* Kg = Kp + (size_t)(b * 2048) * 1024 + h * 64;
  const unsigned short* Vg = Vt + (size_t)bh * 64 * 2048;
  const float* mg = mbias + b * 2048;

  // Q fragments (B-operand of S^T): lane holds Q[q=qt*16+lid][d=ks*32+lg*8..]
  bf16x8 qf[2][2];
#pragma unroll
  for (int qt = 0; qt < 2; qt++)
#pragma unroll
    for (int ks = 0; ks < 2; ks++) {
      int qrow = b * 2048 + q0 + wq + qt * 16 + lid;
      qf[qt][ks] = *(const bf16x8*)(Qp + (size_t)qrow * 1024 + h * 64 + ks * 32 + lg * 8);
    }

  f32x4 Ot[4][2];  // O^T[d=dt*16+lg*4+r][q=qt*16+lid]
#pragma unroll
  for (int dt = 0; dt < 4; dt++)
#pragma unroll
    for (int qt = 0; qt < 2; qt++) Ot[dt][qt] = (f32x4){0.f, 0.f, 0.f, 0.f};
  f32x4 acc_l[2] = {(f32x4){0.f, 0.f, 0.f, 0.f}, (f32x4){0.f, 0.f, 0.f, 0.f}};
  bf16x8 ones8;
#pragma unroll
  for (int i = 0; i < 8; i++) ones8[i] = (__bf16)1.0f;

  // stage one 64-key tile (K 64x64, V^T 64x64) into the given buffer
  auto stage_kv = [&](unsigned short* Kl, unsigned short* Vl, int k0) {
#pragma unroll
    for (int i = 0; i < 2; i++) {
      int c = i * 256 + tid, r = c >> 3, gsw = (c & 7) ^ (r & 7);
      gload16(Kg + (size_t)(k0 + r) * 1024 + gsw * 8, Kl + c * 8);
    }
#pragma unroll
    for (int i = 0; i < 2; i++) {
      int c = i * 256 + tid, d = c >> 3, gsw = (c & 7) ^ (d & 7);
      gload16(Vg + (size_t)d * 2048 + k0 + gsw * 8, Vl + c * 8);
    }
  };

  // QK^T for one q-half; C-init = mask bias from the global table (L2-hit).
  auto qk_half = [&](int kt, const unsigned short* Kl, int qt, f32x4 (&accS)[4]) {
    const float* mrow = mg + kt * 64;
#pragma unroll
    for (int mt = 0; mt < 4; mt++)
      accS[mt] = *(const f32x4*)(&mrow[mt * 16 + lg * 4]);
    __builtin_amdgcn_s_setprio(1);
#pragma unroll
    for (int ks = 0; ks < 2; ks++) {
      int koff = ((ks * 4 + lg) ^ x7) * 8;  // swizzled granule within row
#pragma unroll
      for (int mt = 0; mt < 4; mt++) {
        bf16x8 a = *(const bf16x8*)(&Kl[(mt * 16 + lid) * 64 + koff]);
        accS[mt] = MFMA16(a, qf[qt][ks], accS[mt]);
      }
    }
    __builtin_amdgcn_s_setprio(0);
  };

  // fixed-max softmax for one q-half: p = exp2(score) -> B-frags pb[c]
  auto sm_half = [&](f32x4 (&accS)[4], bf16x8 (&pb)[2]) {
#pragma unroll
    for (int mt = 0; mt < 4; mt++) {
      int half = (mt & 1) * 4;
#pragma unroll
      for (int r = 0; r < 4; r++) {
        float p = __builtin_amdgcn_exp2f(accS[mt][r]);
        pb[mt >> 1][half + r] = (__bf16)p;
      }
    }
  };

  // PV + ones-rowsum, both q-halves (shares the V fragment loads).
  auto pv_joint = [&](bf16x8 (&pb0)[2], bf16x8 (&pb1)[2], const unsigned short* Vl) {
    __builtin_amdgcn_s_setprio(1);
#pragma unroll
    for (int c = 0; c < 2; c++) {
      acc_l[0] = MFMA16(ones8, pb0[c], acc_l[0]);
      acc_l[1] = MFMA16(ones8, pb1[c], acc_l[1]);
    }
    // O^T += V^T . P^T; phys k=lg*8+j <-> key 32*c+16*(j>=4)+lg*4+(j&3)
#pragma unroll
    for (int c = 0; c < 2; c++) {
      int glo = ((4 * c + (lg >> 1)) ^ x7) * 8 + (lg & 1) * 4;
      int ghi = ((4 * c + 2 + (lg >> 1)) ^ x7) * 8 + (lg & 1) * 4;
#pragma unroll
      for (int dt = 0; dt < 4; dt++) {
        const unsigned short* vrow = &Vl[(dt * 16 + lid) * 64];
        bf16x4 lo = *(const bf16x4*)(&vrow[glo]);
        bf16x4 hi = *(const bf16x4*)(&vrow[ghi]);
        bf16x8 av = __builtin_shufflevector(lo, hi, 0, 1, 2, 3, 4, 5, 6, 7);
        Ot[dt][0] = MFMA16(av, pb0[c], Ot[dt][0]);
        Ot[dt][1] = MFMA16(av, pb1[c], Ot[dt][1]);
      }
    }
    __builtin_amdgcn_s_setprio(0);
  };

  // one 64-key tile: q-half-split pipeline. qk(qt1) MFMAs are independent
  // of sm(qt0)'s exp chain; pv's qt0 MFMAs independent of sm(qt1) -> the
  // scheduler interleaves matrix and VALU pipes within this wave.
  auto compute_tile = [&](const unsigned short* Kl, const unsigned short* Vl, int kt) {
    f32x4 accS[4];
    bf16x8 pb0[2], pb1[2];
    qk_half(kt, Kl, 0, accS);
    sm_half(accS, pb0);
    qk_half(kt, Kl, 1, accS);
    sm_half(accS, pb1);
    pv_joint(pb0, pb1, Vl);
  };

  stage_kv(&Klds[0][0], &Vlds[0][0], 0);
  __syncthreads();  // drains vmcnt(0): buf0 ready

  // x2-unrolled: buffer bases compile-time; prefetch issued BEFORE compute,
  // drained by the end-of-tile barrier (implicit vmcnt(0)+lgkmcnt(0)).
  for (int kt = 0; kt < 32; kt += 2) {
    stage_kv(&Klds[1][0], &Vlds[1][0], (kt + 1) * 64);
    compute_tile(&Klds[0][0], &Vlds[0][0], kt);
    __syncthreads();
    if (kt + 2 < 32) stage_kv(&Klds[0][0], &Vlds[0][0], (kt + 2) * 64);
    compute_tile(&Klds[1][0], &Vlds[1][0], kt + 1);
    __syncthreads();
  }

  // epilogue: ctx[q][h*64+d] = O^T/l ; d packed x4 -> 8B stores
#pragma unroll
  for (int qt = 0; qt < 2; qt++) {
    float inv = 1.0f / acc_l[qt][0];
    int qrow = b * 2048 + q0 + wq + qt * 16 + lid;
#pragma unroll
    for (int dt = 0; dt < 4; dt++) {
      ushort4 st;
      st.x = f2bf(Ot[dt][qt][0] * inv);
      st.y = f2bf(Ot[dt][qt][1] * inv);
      st.z = f2bf(Ot[dt][qt][2] * inv);
      st.w = f2bf(Ot[dt][qt][3] * inv);
      *(ushort4*)(&ctx[(size_t)qrow * 1024 + h * 64 + dt * 16 + lg * 4]) = st;
    }
  }
}

// ---------------------------------------------------------------------------
extern "C" void kernel_launch(void* const* d_in, const int* in_sizes, int n_in,
                              void* d_out, int out_size, void* d_ws, size_t ws_size,
                              hipStream_t stream) {
  const float* q  = (const float*)d_in[0];
  const float* k  = (const float*)d_in[1];
  const float* v  = (const float*)d_in[2];
  const int*   mk = (const int*)d_in[3];
  const float* Wq = (const float*)d_in[4];
  const float* bq = (const float*)d_in[5];
  const float* Wk = (const float*)d_in[6];
  const float* bk = (const float*)d_in[7];
  const float* Wv = (const float*)d_in[8];
  const float* bv = (const float*)d_in[9];
  const float* Wo = (const float*)d_in[10];
  const float* bo = (const float*)d_in[11];

  const size_t NTOK = (size_t)8192 * 1024;   // elements per activation tensor
  const size_t NW = (size_t)1024 * 1024;     // elements per weight

  unsigned short* qb  = (unsigned short*)d_ws;
  unsigned short* kb  = qb + NTOK;
  unsigned short* vb  = kb + NTOK;
  unsigned short* Qp  = vb + NTOK;
  unsigned short* Kp  = Qp + NTOK;
  unsigned short* Vt  = Kp + NTOK;
  unsigned short* Wqb = Vt + NTOK;
  unsigned short* Wkb = Wqb + NW;
  unsigned short* Wvb = Wkb + NW;
  unsigned short* Wob = Wvb + NW;
  float*          mbg = (float*)(Wob + NW);  // (B,2048) f32 bias table, 32KB
  unsigned short* ctx = qb;  // qb dead after QKV projections

  CvtJobs J;
  J.j[0] = {q, qb, (int)(NTOK / 8)};
  J.j[1] = {k, kb, (int)(NTOK / 8)};
  J.j[2] = {v, vb, (int)(NTOK / 8)};
  J.j[3] = {Wq, Wqb, (int)(NW / 8)};
  J.j[4] = {Wk, Wkb, (int)(NW / 8)};
  J.j[5] = {Wv, Wvb, (int)(NW / 8)};
  J.j[6] = {Wo, Wob, (int)(NW / 8)};
  J.j[7] = {(const float*)mk, (unsigned short*)mbg, 2048};  // mask -> bias
  cvt_all<<<dim3(4096, 8), 256, 0, stream>>>(J);

  ProjJobs P;
  P.j[0] = {qb, Wqb, bq, Qp, SCALE_Q};
  P.j[1] = {kb, Wkb, bk, Kp, 1.0f};
  P.j[2] = {vb, Wvb, bv, Vt, 1.0f};
  gemm_qkv<<<dim3(8, 64, 3), 256, 0, stream>>>(P);

  attn<<<dim3(16, 64), 256, 0, stream>>>(Qp, Kp, Vt, mbg, ctx);
  gemm_o<<<dim3(8, 64), 256, 0, stream>>>(ctx, Wob, bo, (float*)d_out);
}

// Round 7
// 341.706 us; speedup vs baseline: 1.4686x; 1.0345x over previous
//
#include <hip/hip_runtime.h>

// ---------------------------------------------------------------------------
// MultiHeadAttention: B=4, S=2048, D=1024, H=16, Dh=64. FP32 I/O.
// cvt-all-to-bf16 (+mask->bias table) -> merged QKV GEMM (XCD-swizzled) ->
// flash attention (fixed-max softmax; q-half-split compute; 64-key dbuf;
// XCD-sharded (b,h)) -> out GEMM (XCD-swizzled, f32 out).
// ---------------------------------------------------------------------------

typedef __bf16 bf16x8 __attribute__((ext_vector_type(8)));
typedef __bf16 bf16x4 __attribute__((ext_vector_type(4)));
typedef float  f32x4  __attribute__((ext_vector_type(4)));

#define LOG2E 1.44269504088896340736f
#define SCALE_Q (0.125f * LOG2E)      // 1/sqrt(64) * log2(e), folded into Q
#define MBIAS_L2 (-1.44269504e9f)     // -1e9 * log2(e)
#define MFMA16(a, b, c) __builtin_amdgcn_mfma_f32_16x16x32_bf16(a, b, c, 0, 0, 0)

__device__ inline unsigned short f2bf(float f) {  // RNE f32 -> bf16 bits
  unsigned int u = __float_as_uint(f);
  u = u + 0x7FFF + ((u >> 16) & 1);
  return (unsigned short)(u >> 16);
}
__device__ inline void gload16(const void* g, void* l) {  // 16B global->LDS DMA
  __builtin_amdgcn_global_load_lds(
      (const __attribute__((address_space(1))) void*)g,
      (__attribute__((address_space(3))) void*)l, 16, 0, 0);
}
__device__ inline bf16x8 cvt8(const float* p) {  // 8 f32 -> bf16x8
  float4 a = *(const float4*)p, b = *(const float4*)(p + 4);
  bf16x8 v;
  v[0] = (__bf16)a.x; v[1] = (__bf16)a.y; v[2] = (__bf16)a.z; v[3] = (__bf16)a.w;
  v[4] = (__bf16)b.x; v[5] = (__bf16)b.y; v[6] = (__bf16)b.z; v[7] = (__bf16)b.w;
  return v;
}

// ---------------------------------------------------------------------------
// cvt_all: f32 -> bf16, 7 jobs (q,k,v,Wq,Wk,Wv,Wo) + job 7: mask int ->
// f32 bias table (0 / -1e9*log2e). grid (4096, 8), 256 thr.
// ---------------------------------------------------------------------------
struct CvtJob { const float* s; unsigned short* d; int n8; };
struct CvtJobs { CvtJob j[8]; };
__global__ void cvt_all(CvtJobs J) {
  CvtJob jb = J.j[blockIdx.y];
  int i = blockIdx.x * 256 + threadIdx.x;
  if (blockIdx.y == 7) {  // mask -> bias (8192 ints, int4/thread)
    if (i < jb.n8) {
      int4 m = ((const int4*)jb.s)[i];
      float4 o;
      o.x = m.x ? 0.f : MBIAS_L2;
      o.y = m.y ? 0.f : MBIAS_L2;
      o.z = m.z ? 0.f : MBIAS_L2;
      o.w = m.w ? 0.f : MBIAS_L2;
      ((float4*)jb.d)[i] = o;
    }
    return;
  }
  if (i < jb.n8) *(bf16x8*)(jb.d + (size_t)i * 8) = cvt8(jb.s + (size_t)i * 8);
}

// ---------------------------------------------------------------------------
// gemm_qkv: merged Q/K/V projections, one dispatch, grid (8, 64, 3).
// z in {0:Q, 1:K} swapped orientation (token-packed col-major stores);
// z==2 (V) normal orientation, writes Vt[(b*16+h)*64+d][s] directly.
// XCD swizzle (T1): default round-robin puts wg&7 on XCD wg&7, so the 8
// c0-blocks sharing one A-panel land on 8 DIFFERENT XCDs -> A re-fetched 8x
// (FETCH 201MB vs ~110 ideal). Remap so each XCD owns 8 t0-panels x all 8
// c0: A-panels L2-local (2MB) + W replicated (2MB) = 4MB/XCD = L2 size.
// ---------------------------------------------------------------------------
struct ProjJob { const unsigned short* A; const unsigned short* W;
                 const float* bias; unsigned short* out; float scale; };
struct ProjJobs { ProjJob j[3]; };

__global__ __launch_bounds__(256, 2) void gemm_qkv(ProjJobs J) {
  __shared__ __align__(16) unsigned short Al[128 * 32];
  __shared__ __align__(16) unsigned short Wl[128 * 32];
  const int z = blockIdx.z;
  const ProjJob jb = J.j[z];
  const int tid = threadIdx.x, lane = tid & 63, w = tid >> 6;
  const int lid = lane & 15, lg = lane >> 4;
  // XCD swizzle: bijective over 512 blocks/z; z*512 preserves wg&7.
  const int lin = blockIdx.x + 8 * (int)blockIdx.y;
  const int xcd = lin & 7, j = lin >> 3;
  const int c0 = (j & 7) * 128;
  const int t0 = ((j >> 3) * 8 + xcd) * 128;
  const int wm = (w & 1) * 64, wn = (w >> 1) * 64;
  const unsigned short* Ml = (z == 2) ? Al : Wl;
  const unsigned short* Nl = (z == 2) ? Wl : Al;

  f32x4 acc[4][4];
#pragma unroll
  for (int i = 0; i < 4; i++)
#pragma unroll
    for (int jj = 0; jj < 4; jj++) acc[i][jj] = (f32x4){0.f, 0.f, 0.f, 0.f};

  for (int kt = 0; kt < 1024; kt += 32) {
    __syncthreads();
#pragma unroll
    for (int i = 0; i < 2; i++) {
      int c = i * 256 + tid, r = c >> 2, ko = (c & 3) * 8;
      gload16(jb.A + (size_t)(t0 + r) * 1024 + kt + ko, &Al[c * 8]);
      gload16(jb.W + (size_t)(c0 + r) * 1024 + kt + ko, &Wl[c * 8]);
    }
    __syncthreads();
    bf16x8 mf[4], nf[4];
#pragma unroll
    for (int mi = 0; mi < 4; mi++)
      mf[mi] = *(const bf16x8*)(&Ml[(wm + mi * 16 + lid) * 32 + lg * 8]);
#pragma unroll
    for (int ni = 0; ni < 4; ni++)
      nf[ni] = *(const bf16x8*)(&Nl[(wn + ni * 16 + lid) * 32 + lg * 8]);
#pragma unroll
    for (int mi = 0; mi < 4; mi++)
#pragma unroll
      for (int ni = 0; ni < 4; ni++)
        acc[mi][ni] = MFMA16(mf[mi], nf[ni], acc[mi][ni]);
  }

  if (z < 2) {
    const float scale = jb.scale;
#pragma unroll
    for (int mi = 0; mi < 4; mi++) {
      int colb = c0 + wm + mi * 16 + lg * 4;
      float4 b4 = *(const float4*)(&jb.bias[colb]);
#pragma unroll
      for (int ni = 0; ni < 4; ni++) {
        int token = t0 + wn + ni * 16 + lid;
        ushort4 st;
        st.x = f2bf((acc[mi][ni][0] + b4.x) * scale);
        st.y = f2bf((acc[mi][ni][1] + b4.y) * scale);
        st.z = f2bf((acc[mi][ni][2] + b4.z) * scale);
        st.w = f2bf((acc[mi][ni][3] + b4.w) * scale);
        *(ushort4*)(&jb.out[(size_t)token * 1024 + colb]) = st;
      }
    }
  } else {
    const int b = t0 >> 11;  // whole 128-token tile lies in one batch
#pragma unroll
    for (int ni = 0; ni < 4; ni++) {
      int col = c0 + wn + ni * 16 + lid;
      int h = col >> 6, d = col & 63;
      float bv = jb.bias[col];
#pragma unroll
      for (int mi = 0; mi < 4; mi++) {
        int s = (t0 & 2047) + wm + mi * 16 + lg * 4;
        ushort4 st;
        st.x = f2bf(acc[mi][ni][0] + bv);
        st.y = f2bf(acc[mi][ni][1] + bv);
        st.z = f2bf(acc[mi][ni][2] + bv);
        st.w = f2bf(acc[mi][ni][3] + bv);
        *(ushort4*)(&jb.out[(size_t)((b * 16 + h) * 64 + d) * 2048 + s]) = st;
      }
    }
  }
}

// ---------------------------------------------------------------------------
// gemm_o: f32 C[token][col] = A_bf16 @ W_bf16^T + bias. grid (8, 64).
// Same XCD swizzle as gemm_qkv.
// ---------------------------------------------------------------------------
__global__ __launch_bounds__(256, 2) void gemm_o(
    const unsigned short* __restrict__ A, const unsigned short* __restrict__ W,
    const float* __restrict__ bias, float* __restrict__ C) {
  __shared__ __align__(16) unsigned short Al[128 * 32];
  __shared__ __align__(16) unsigned short Wl[128 * 32];
  const int tid = threadIdx.x, lane = tid & 63, w = tid >> 6;
  const int lid = lane & 15, lg = lane >> 4;
  const int lin = blockIdx.x + 8 * (int)blockIdx.y;
  const int xcd = lin & 7, j = lin >> 3;
  const int c0 = (j & 7) * 128;
  const int t0 = ((j >> 3) * 8 + xcd) * 128;
  const int wc = (w & 1) * 64, wt = (w >> 1) * 64;
  f32x4 acc[4][4];
#pragma unroll
  for (int i = 0; i < 4; i++)
#pragma unroll
    for (int jj = 0; jj < 4; jj++) acc[i][jj] = (f32x4){0.f, 0.f, 0.f, 0.f};

  for (int kt = 0; kt < 1024; kt += 32) {
    __syncthreads();
#pragma unroll
    for (int i = 0; i < 2; i++) {
      int c = i * 256 + tid, r = c >> 2, ko = (c & 3) * 8;
      gload16(A + (size_t)(t0 + r) * 1024 + kt + ko, &Al[c * 8]);
      gload16(W + (size_t)(c0 + r) * 1024 + kt + ko, &Wl[c * 8]);
    }
    __syncthreads();
    bf16x8 aw[4], bt[4];
#pragma unroll
    for (int mi = 0; mi < 4; mi++)
      aw[mi] = *(const bf16x8*)(&Wl[(wc + mi * 16 + lid) * 32 + lg * 8]);
#pragma unroll
    for (int ni = 0; ni < 4; ni++)
      bt[ni] = *(const bf16x8*)(&Al[(wt + ni * 16 + lid) * 32 + lg * 8]);
#pragma unroll
    for (int mi = 0; mi < 4; mi++)
#pragma unroll
      for (int ni = 0; ni < 4; ni++)
        acc[mi][ni] = MFMA16(aw[mi], bt[ni], acc[mi][ni]);
  }
#pragma unroll
  for (int mi = 0; mi < 4; mi++) {
    int colb = c0 + wc + mi * 16 + lg * 4;
    float4 b4 = *(const float4*)(&bias[colb]);
#pragma unroll
    for (int ni = 0; ni < 4; ni++) {
      int token = t0 + wt + ni * 16 + lid;
      float4 st;
      st.x = acc[mi][ni][0] + b4.x;
      st.y = acc[mi][ni][1] + b4.y;
      st.z = acc[mi][ni][2] + b4.z;
      st.w = acc[mi][ni][3] + b4.w;
      *(float4*)(&C[(size_t)token * 1024 + colb]) = st;
    }
  }
}

// ---------------------------------------------------------------------------
// Flash attention v9: q-half-split compute, 128-reg class (unchanged from
// R6 — steady-state <90us, no spill, VGPR 64).
// ---------------------------------------------------------------------------
__global__ __launch_bounds__(256, 4) void attn(
    const unsigned short* __restrict__ Qp,   // (B*S, 1024), pre-scaled
    const unsigned short* __restrict__ Kp,   // (B*S, 1024)
    const unsigned short* __restrict__ Vt,   // (B*H, 64, 2048)
    const float* __restrict__ mbias,         // (B, 2048) f32 bias table
    unsigned short* __restrict__ ctx) {      // (B*S, 1024)
  __shared__ __align__(16) unsigned short Klds[2][64 * 64];  // [key][d], XOR-swz
  __shared__ __align__(16) unsigned short Vlds[2][64 * 64];  // [d][key], XOR-swz

  const int tid = threadIdx.x, lane = tid & 63, w = tid >> 6;
  const int lid = lane & 15, lg = lane >> 4;
  // XCD shard: wg -> (xcd, idx); bh = xcd*8 + idx/16 so one (b,h)'s 16
  // q-blocks stay on one XCD's L2. Bijective over 1024 = 8*8*16.
  const int wg = blockIdx.x + (int)(gridDim.x) * blockIdx.y;
  const int xcd = wg & 7, idx = wg >> 3;
  const int bh = (xcd << 3) | (idx >> 4);
  const int q0 = (idx & 15) * 128;
  const int b = bh >> 4, h = bh & 15;
  const int wq = w * 32;
  const int x7 = lid & 7;  // XOR swizzle key (row&7 == lid&7 for all reads)

  const unsigned short* Kg = Kp + (size_t)(b * 2048) * 1024 + h * 64;
  const unsigned short* Vg = Vt + (size_t)bh * 64 * 2048;
  const float* mg = mbias + b * 2048;

  // Q fragments (B-operand of S^T): lane holds Q[q=qt*16+lid][d=ks*32+lg*8..]
  bf16x8 qf[2][2];
#pragma unroll
  for (int qt = 0; qt < 2; qt++)
#pragma unroll
    for (int ks = 0; ks < 2; ks++) {
      int qrow = b * 2048 + q0 + wq + qt * 16 + lid;
      qf[qt][ks] = *(const bf16x8*)(Qp + (size_t)qrow * 1024 + h * 64 + ks * 32 + lg * 8);
    }

  f32x4 Ot[4][2];  // O^T[d=dt*16+lg*4+r][q=qt*16+lid]
#pragma unroll
  for (int dt = 0; dt < 4; dt++)
#pragma unroll
    for (int qt = 0; qt < 2; qt++) Ot[dt][qt] = (f32x4){0.f, 0.f, 0.f, 0.f};
  f32x4 acc_l[2] = {(f32x4){0.f, 0.f, 0.f, 0.f}, (f32x4){0.f, 0.f, 0.f, 0.f}};
  bf16x8 ones8;
#pragma unroll
  for (int i = 0; i < 8; i++) ones8[i] = (__bf16)1.0f;

  // stage one 64-key tile (K 64x64, V^T 64x64) into the given buffer
  auto stage_kv = [&](unsigned short* Kl, unsigned short* Vl, int k0) {
#pragma unroll
    for (int i = 0; i < 2; i++) {
      int c = i * 256 + tid, r = c >> 3, gsw = (c & 7) ^ (r & 7);
      gload16(Kg + (size_t)(k0 + r) * 1024 + gsw * 8, Kl + c * 8);
    }
#pragma unroll
    for (int i = 0; i < 2; i++) {
      int c = i * 256 + tid, d = c >> 3, gsw = (c & 7) ^ (d & 7);
      gload16(Vg + (size_t)d * 2048 + k0 + gsw * 8, Vl + c * 8);
    }
  };

  // QK^T for one q-half; C-init = mask bias from the global table (L2-hit).
  auto qk_half = [&](int kt, const unsigned short* Kl, int qt, f32x4 (&accS)[4]) {
    const float* mrow = mg + kt * 64;
#pragma unroll
    for (int mt = 0; mt < 4; mt++)
      accS[mt] = *(const f32x4*)(&mrow[mt * 16 + lg * 4]);
    __builtin_amdgcn_s_setprio(1);
#pragma unroll
    for (int ks = 0; ks < 2; ks++) {
      int koff = ((ks * 4 + lg) ^ x7) * 8;  // swizzled granule within row
#pragma unroll
      for (int mt = 0; mt < 4; mt++) {
        bf16x8 a = *(const bf16x8*)(&Kl[(mt * 16 + lid) * 64 + koff]);
        accS[mt] = MFMA16(a, qf[qt][ks], accS[mt]);
      }
    }
    __builtin_amdgcn_s_setprio(0);
  };

  // fixed-max softmax for one q-half: p = exp2(score) -> B-frags pb[c]
  auto sm_half = [&](f32x4 (&accS)[4], bf16x8 (&pb)[2]) {
#pragma unroll
    for (int mt = 0; mt < 4; mt++) {
      int half = (mt & 1) * 4;
#pragma unroll
      for (int r = 0; r < 4; r++) {
        float p = __builtin_amdgcn_exp2f(accS[mt][r]);
        pb[mt >> 1][half + r] = (__bf16)p;
      }
    }
  };

  // PV + ones-rowsum, both q-halves (shares the V fragment loads).
  auto pv_joint = [&](bf16x8 (&pb0)[2], bf16x8 (&pb1)[2], const unsigned short* Vl) {
    __builtin_amdgcn_s_setprio(1);
#pragma unroll
    for (int c = 0; c < 2; c++) {
      acc_l[0] = MFMA16(ones8, pb0[c], acc_l[0]);
      acc_l[1] = MFMA16(ones8, pb1[c], acc_l[1]);
    }
    // O^T += V^T . P^T; phys k=lg*8+j <-> key 32*c+16*(j>=4)+lg*4+(j&3)
#pragma unroll
    for (int c = 0; c < 2; c++) {
      int glo = ((4 * c + (lg >> 1)) ^ x7) * 8 + (lg & 1) * 4;
      int ghi = ((4 * c + 2 + (lg >> 1)) ^ x7) * 8 + (lg & 1) * 4;
#pragma unroll
      for (int dt = 0; dt < 4; dt++) {
        const unsigned short* vrow = &Vl[(dt * 16 + lid) * 64];
        bf16x4 lo = *(const bf16x4*)(&vrow[glo]);
        bf16x4 hi = *(const bf16x4*)(&vrow[ghi]);
        bf16x8 av = __builtin_shufflevector(lo, hi, 0, 1, 2, 3, 4, 5, 6, 7);
        Ot[dt][0] = MFMA16(av, pb0[c], Ot[dt][0]);
        Ot[dt][1] = MFMA16(av, pb1[c], Ot[dt][1]);
      }
    }
    __builtin_amdgcn_s_setprio(0);
  };

  // one 64-key tile: q-half-split pipeline. qk(qt1) MFMAs are independent
  // of sm(qt0)'s exp chain; pv's qt0 MFMAs independent of sm(qt1) -> the
  // scheduler interleaves matrix and VALU pipes within this wave.
  auto compute_tile = [&](const unsigned short* Kl, const unsigned short* Vl, int kt) {
    f32x4 accS[4];
    bf16x8 pb0[2], pb1[2];
    qk_half(kt, Kl, 0, accS);
    sm_half(accS, pb0);
    qk_half(kt, Kl, 1, accS);
    sm_half(accS, pb1);
    pv_joint(pb0, pb1, Vl);
  };

  stage_kv(&Klds[0][0], &Vlds[0][0], 0);
  __syncthreads();  // drains vmcnt(0): buf0 ready

  // x2-unrolled: buffer bases compile-time; prefetch issued BEFORE compute,
  // drained by the end-of-tile barrier (implicit vmcnt(0)+lgkmcnt(0)).
  for (int kt = 0; kt < 32; kt += 2) {
    stage_kv(&Klds[1][0], &Vlds[1][0], (kt + 1) * 64);
    compute_tile(&Klds[0][0], &Vlds[0][0], kt);
    __syncthreads();
    if (kt + 2 < 32) stage_kv(&Klds[0][0], &Vlds[0][0], (kt + 2) * 64);
    compute_tile(&Klds[1][0], &Vlds[1][0], kt + 1);
    __syncthreads();
  }

  // epilogue: ctx[q][h*64+d] = O^T/l ; d packed x4 -> 8B stores
#pragma unroll
  for (int qt = 0; qt < 2; qt++) {
    float inv = 1.0f / acc_l[qt][0];
    int qrow = b * 2048 + q0 + wq + qt * 16 + lid;
#pragma unroll
    for (int dt = 0; dt < 4; dt++) {
      ushort4 st;
      st.x = f2bf(Ot[dt][qt][0] * inv);
      st.y = f2bf(Ot[dt][qt][1] * inv);
      st.z = f2bf(Ot[dt][qt][2] * inv);
      st.w = f2bf(Ot[dt][qt][3] * inv);
      *(ushort4*)(&ctx[(size_t)qrow * 1024 + h * 64 + dt * 16 + lg * 4]) = st;
    }
  }
}

// ---------------------------------------------------------------------------
extern "C" void kernel_launch(void* const* d_in, const int* in_sizes, int n_in,
                              void* d_out, int out_size, void* d_ws, size_t ws_size,
                              hipStream_t stream) {
  const float* q  = (const float*)d_in[0];
  const float* k  = (const float*)d_in[1];
  const float* v  = (const float*)d_in[2];
  const int*   mk = (const int*)d_in[3];
  const float* Wq = (const float*)d_in[4];
  const float* bq = (const float*)d_in[5];
  const float* Wk = (const float*)d_in[6];
  const float* bk = (const float*)d_in[7];
  const float* Wv = (const float*)d_in[8];
  const float* bv = (const float*)d_in[9];
  const float* Wo = (const float*)d_in[10];
  const float* bo = (const float*)d_in[11];

  const size_t NTOK = (size_t)8192 * 1024;   // elements per activation tensor
  const size_t NW = (size_t)1024 * 1024;     // elements per weight

  unsigned short* qb  = (unsigned short*)d_ws;
  unsigned short* kb  = qb + NTOK;
  unsigned short* vb  = kb + NTOK;
  unsigned short* Qp  = vb + NTOK;
  unsigned short* Kp  = Qp + NTOK;
  unsigned short* Vt  = Kp + NTOK;
  unsigned short* Wqb = Vt + NTOK;
  unsigned short* Wkb = Wqb + NW;
  unsigned short* Wvb = Wkb + NW;
  unsigned short* Wob = Wvb + NW;
  float*          mbg = (float*)(Wob + NW);  // (B,2048) f32 bias table, 32KB
  unsigned short* ctx = qb;  // qb dead after QKV projections

  CvtJobs J;
  J.j[0] = {q, qb, (int)(NTOK / 8)};
  J.j[1] = {k, kb, (int)(NTOK / 8)};
  J.j[2] = {v, vb, (int)(NTOK / 8)};
  J.j[3] = {Wq, Wqb, (int)(NW / 8)};
  J.j[4] = {Wk, Wkb, (int)(NW / 8)};
  J.j[5] = {Wv, Wvb, (int)(NW / 8)};
  J.j[6] = {Wo, Wob, (int)(NW / 8)};
  J.j[7] = {(const float*)mk, (unsigned short*)mbg, 2048};  // mask -> bias
  cvt_all<<<dim3(4096, 8), 256, 0, stream>>>(J);

  ProjJobs P;
  P.j[0] = {qb, Wqb, bq, Qp, SCALE_Q};
  P.j[1] = {kb, Wkb, bk, Kp, 1.0f};
  P.j[2] = {vb, Wvb, bv, Vt, 1.0f};
  gemm_qkv<<<dim3(8, 64, 3), 256, 0, stream>>>(P);

  attn<<<dim3(16, 64), 256, 0, stream>>>(Qp, Kp, Vt, mbg, ctx);
  gemm_o<<<dim3(8, 64), 256, 0, stream>>>(ctx, Wob, bo, (float*)d_out);
}

// Round 8
// 338.635 us; speedup vs baseline: 1.4819x; 1.0091x over previous
//
#include <hip/hip_runtime.h>

// ---------------------------------------------------------------------------
// MultiHeadAttention: B=4, S=2048, D=1024, H=16, Dh=64. FP32 I/O.
// cvt-all-to-bf16 (+mask->bias table) -> merged QKV GEMM (XCD-swizzled,
// single-barrier dbuf prefetch) -> flash attention (fixed-max softmax;
// q-half-split; 64-key dbuf; XCD-sharded) -> out GEMM (same dbuf, f32 out).
// ---------------------------------------------------------------------------

typedef __bf16 bf16x8 __attribute__((ext_vector_type(8)));
typedef __bf16 bf16x4 __attribute__((ext_vector_type(4)));
typedef float  f32x4  __attribute__((ext_vector_type(4)));

#define LOG2E 1.44269504088896340736f
#define SCALE_Q (0.125f * LOG2E)      // 1/sqrt(64) * log2(e), folded into Q
#define MBIAS_L2 (-1.44269504e9f)     // -1e9 * log2(e)
#define MFMA16(a, b, c) __builtin_amdgcn_mfma_f32_16x16x32_bf16(a, b, c, 0, 0, 0)

__device__ inline unsigned short f2bf(float f) {  // RNE f32 -> bf16 bits
  unsigned int u = __float_as_uint(f);
  u = u + 0x7FFF + ((u >> 16) & 1);
  return (unsigned short)(u >> 16);
}
__device__ inline void gload16(const void* g, void* l) {  // 16B global->LDS DMA
  __builtin_amdgcn_global_load_lds(
      (const __attribute__((address_space(1))) void*)g,
      (__attribute__((address_space(3))) void*)l, 16, 0, 0);
}
__device__ inline bf16x8 cvt8(const float* p) {  // 8 f32 -> bf16x8
  float4 a = *(const float4*)p, b = *(const float4*)(p + 4);
  bf16x8 v;
  v[0] = (__bf16)a.x; v[1] = (__bf16)a.y; v[2] = (__bf16)a.z; v[3] = (__bf16)a.w;
  v[4] = (__bf16)b.x; v[5] = (__bf16)b.y; v[6] = (__bf16)b.z; v[7] = (__bf16)b.w;
  return v;
}

// ---------------------------------------------------------------------------
// cvt_all: f32 -> bf16, 7 jobs (q,k,v,Wq,Wk,Wv,Wo) + job 7: mask int ->
// f32 bias table (0 / -1e9*log2e). grid (4096, 8), 256 thr.
// ---------------------------------------------------------------------------
struct CvtJob { const float* s; unsigned short* d; int n8; };
struct CvtJobs { CvtJob j[8]; };
__global__ void cvt_all(CvtJobs J) {
  CvtJob jb = J.j[blockIdx.y];
  int i = blockIdx.x * 256 + threadIdx.x;
  if (blockIdx.y == 7) {  // mask -> bias (8192 ints, int4/thread)
    if (i < jb.n8) {
      int4 m = ((const int4*)jb.s)[i];
      float4 o;
      o.x = m.x ? 0.f : MBIAS_L2;
      o.y = m.y ? 0.f : MBIAS_L2;
      o.z = m.z ? 0.f : MBIAS_L2;
      o.w = m.w ? 0.f : MBIAS_L2;
      ((float4*)jb.d)[i] = o;
    }
    return;
  }
  if (i < jb.n8) *(bf16x8*)(jb.d + (size_t)i * 8) = cvt8(jb.s + (size_t)i * 8);
}

// ---------------------------------------------------------------------------
// gemm_qkv: merged Q/K/V projections, one dispatch, grid (8, 64, 3).
// z in {0:Q, 1:K} swapped orientation (token-packed col-major stores);
// z==2 (V) normal orientation, writes Vt[(b*16+h)*64+d][s] directly.
// XCD swizzle (T1, R7-verified): each XCD owns 8 t0-panels x all 8 c0 ->
// A-panels L2-local. NEW (R8): single-barrier dbuf prefetch — stage K-step
// k+1 BEFORE compute of step k; the end-of-step barrier's implicit vmcnt(0)
// lands the prefetch. Removes the per-step HBM round-trip stall of the
// 2-barrier shape (GEMMs were ~23% MfmaUtil). LDS 32KB.
// ---------------------------------------------------------------------------
struct ProjJob { const unsigned short* A; const unsigned short* W;
                 const float* bias; unsigned short* out; float scale; };
struct ProjJobs { ProjJob j[3]; };

__global__ __launch_bounds__(256, 2) void gemm_qkv(ProjJobs J) {
  __shared__ __align__(16) unsigned short Al[2][128 * 32];
  __shared__ __align__(16) unsigned short Wl[2][128 * 32];
  const int z = blockIdx.z;
  const ProjJob jb = J.j[z];
  const int tid = threadIdx.x, lane = tid & 63, w = tid >> 6;
  const int lid = lane & 15, lg = lane >> 4;
  // XCD swizzle: bijective over 512 blocks/z; z*512 preserves wg&7.
  const int lin = blockIdx.x + 8 * (int)blockIdx.y;
  const int xcd = lin & 7, j = lin >> 3;
  const int c0 = (j & 7) * 128;
  const int t0 = ((j >> 3) * 8 + xcd) * 128;
  const int wm = (w & 1) * 64, wn = (w >> 1) * 64;

  f32x4 acc[4][4];
#pragma unroll
  for (int i = 0; i < 4; i++)
#pragma unroll
    for (int jj = 0; jj < 4; jj++) acc[i][jj] = (f32x4){0.f, 0.f, 0.f, 0.f};

  auto stage = [&](int bi, int kt) {
#pragma unroll
    for (int i = 0; i < 2; i++) {
      int c = i * 256 + tid, r = c >> 2, ko = (c & 3) * 8;
      gload16(jb.A + (size_t)(t0 + r) * 1024 + kt + ko, &Al[bi][c * 8]);
      gload16(jb.W + (size_t)(c0 + r) * 1024 + kt + ko, &Wl[bi][c * 8]);
    }
  };
  auto compute = [&](int bi) {
    const unsigned short* Ml = (z == 2) ? Al[bi] : Wl[bi];
    const unsigned short* Nl = (z == 2) ? Wl[bi] : Al[bi];
    bf16x8 mf[4], nf[4];
#pragma unroll
    for (int mi = 0; mi < 4; mi++)
      mf[mi] = *(const bf16x8*)(&Ml[(wm + mi * 16 + lid) * 32 + lg * 8]);
#pragma unroll
    for (int ni = 0; ni < 4; ni++)
      nf[ni] = *(const bf16x8*)(&Nl[(wn + ni * 16 + lid) * 32 + lg * 8]);
#pragma unroll
    for (int mi = 0; mi < 4; mi++)
#pragma unroll
      for (int ni = 0; ni < 4; ni++)
        acc[mi][ni] = MFMA16(mf[mi], nf[ni], acc[mi][ni]);
  };

  stage(0, 0);
  __syncthreads();
  // x2-unrolled: prefetch k+1 before compute k; 1 barrier/K-step.
  for (int kt = 0; kt < 1024; kt += 64) {
    stage(1, kt + 32);                     // kt+32 <= 992: always valid
    compute(0);
    __syncthreads();
    if (kt + 64 < 1024) stage(0, kt + 64);
    compute(1);
    __syncthreads();
  }

  if (z < 2) {
    const float scale = jb.scale;
#pragma unroll
    for (int mi = 0; mi < 4; mi++) {
      int colb = c0 + wm + mi * 16 + lg * 4;
      float4 b4 = *(const float4*)(&jb.bias[colb]);
#pragma unroll
      for (int ni = 0; ni < 4; ni++) {
        int token = t0 + wn + ni * 16 + lid;
        ushort4 st;
        st.x = f2bf((acc[mi][ni][0] + b4.x) * scale);
        st.y = f2bf((acc[mi][ni][1] + b4.y) * scale);
        st.z = f2bf((acc[mi][ni][2] + b4.z) * scale);
        st.w = f2bf((acc[mi][ni][3] + b4.w) * scale);
        *(ushort4*)(&jb.out[(size_t)token * 1024 + colb]) = st;
      }
    }
  } else {
    const int b = t0 >> 11;  // whole 128-token tile lies in one batch
#pragma unroll
    for (int ni = 0; ni < 4; ni++) {
      int col = c0 + wn + ni * 16 + lid;
      int h = col >> 6, d = col & 63;
      float bv = jb.bias[col];
#pragma unroll
      for (int mi = 0; mi < 4; mi++) {
        int s = (t0 & 2047) + wm + mi * 16 + lg * 4;
        ushort4 st;
        st.x = f2bf(acc[mi][ni][0] + bv);
        st.y = f2bf(acc[mi][ni][1] + bv);
        st.z = f2bf(acc[mi][ni][2] + bv);
        st.w = f2bf(acc[mi][ni][3] + bv);
        *(ushort4*)(&jb.out[(size_t)((b * 16 + h) * 64 + d) * 2048 + s]) = st;
      }
    }
  }
}

// ---------------------------------------------------------------------------
// gemm_o: f32 C[token][col] = A_bf16 @ W_bf16^T + bias. grid (8, 64).
// Same XCD swizzle + single-barrier dbuf as gemm_qkv.
// ---------------------------------------------------------------------------
__global__ __launch_bounds__(256, 2) void gemm_o(
    const unsigned short* __restrict__ A, const unsigned short* __restrict__ W,
    const float* __restrict__ bias, float* __restrict__ C) {
  __shared__ __align__(16) unsigned short Al[2][128 * 32];
  __shared__ __align__(16) unsigned short Wl[2][128 * 32];
  const int tid = threadIdx.x, lane = tid & 63, w = tid >> 6;
  const int lid = lane & 15, lg = lane >> 4;
  const int lin = blockIdx.x + 8 * (int)blockIdx.y;
  const int xcd = lin & 7, j = lin >> 3;
  const int c0 = (j & 7) * 128;
  const int t0 = ((j >> 3) * 8 + xcd) * 128;
  const int wc = (w & 1) * 64, wt = (w >> 1) * 64;
  f32x4 acc[4][4];
#pragma unroll
  for (int i = 0; i < 4; i++)
#pragma unroll
    for (int jj = 0; jj < 4; jj++) acc[i][jj] = (f32x4){0.f, 0.f, 0.f, 0.f};

  auto stage = [&](int bi, int kt) {
#pragma unroll
    for (int i = 0; i < 2; i++) {
      int c = i * 256 + tid, r = c >> 2, ko = (c & 3) * 8;
      gload16(A + (size_t)(t0 + r) * 1024 + kt + ko, &Al[bi][c * 8]);
      gload16(W + (size_t)(c0 + r) * 1024 + kt + ko, &Wl[bi][c * 8]);
    }
  };
  auto compute = [&](int bi) {
    bf16x8 aw[4], bt[4];
#pragma unroll
    for (int mi = 0; mi < 4; mi++)
      aw[mi] = *(const bf16x8*)(&Wl[bi][(wc + mi * 16 + lid) * 32 + lg * 8]);
#pragma unroll
    for (int ni = 0; ni < 4; ni++)
      bt[ni] = *(const bf16x8*)(&Al[bi][(wt + ni * 16 + lid) * 32 + lg * 8]);
#pragma unroll
    for (int mi = 0; mi < 4; mi++)
#pragma unroll
      for (int ni = 0; ni < 4; ni++)
        acc[mi][ni] = MFMA16(aw[mi], bt[ni], acc[mi][ni]);
  };

  stage(0, 0);
  __syncthreads();
  for (int kt = 0; kt < 1024; kt += 64) {
    stage(1, kt + 32);
    compute(0);
    __syncthreads();
    if (kt + 64 < 1024) stage(0, kt + 64);
    compute(1);
    __syncthreads();
  }
#pragma unroll
  for (int mi = 0; mi < 4; mi++) {
    int colb = c0 + wc + mi * 16 + lg * 4;
    float4 b4 = *(const float4*)(&bias[colb]);
#pragma unroll
    for (int ni = 0; ni < 4; ni++) {
      int token = t0 + wt + ni * 16 + lid;
      float4 st;
      st.x = acc[mi][ni][0] + b4.x;
      st.y = acc[mi][ni][1] + b4.y;
      st.z = acc[mi][ni][2] + b4.z;
      st.w = acc[mi][ni][3] + b4.w;
      *(float4*)(&C[(size_t)token * 1024 + colb]) = st;
    }
  }
}

// ---------------------------------------------------------------------------
// Flash attention v9: q-half-split compute, 128-reg class (unchanged —
// steady-state 85.8us, no spill, VGPR 64, grid-capacity-limited).
// ---------------------------------------------------------------------------
__global__ __launch_bounds__(256, 4) void attn(
    const unsigned short* __restrict__ Qp,   // (B*S, 1024), pre-scaled
    const unsigned short* __restrict__ Kp,   // (B*S, 1024)
    const unsigned short* __restrict__ Vt,   // (B*H, 64, 2048)
    const float* __restrict__ mbias,         // (B, 2048) f32 bias table
    unsigned short* __restrict__ ctx) {      // (B*S, 1024)
  __shared__ __align__(16) unsigned short Klds[2][64 * 64];  // [key][d], XOR-swz
  __shared__ __align__(16) unsigned short Vlds[2][64 * 64];  // [d][key], XOR-swz

  const int tid = threadIdx.x, lane = tid & 63, w = tid >> 6;
  const int lid = lane & 15, lg = lane >> 4;
  // XCD shard: wg -> (xcd, idx); bh = xcd*8 + idx/16 so one (b,h)'s 16
  // q-blocks stay on one XCD's L2. Bijective over 1024 = 8*8*16.
  const int wg = blockIdx.x + (int)(gridDim.x) * blockIdx.y;
  const int xcd = wg & 7, idx = wg >> 3;
  const int bh = (xcd << 3) | (idx >> 4);
  const int q0 = (idx & 15) * 128;
  const int b = bh >> 4, h = bh & 15;
  const int wq = w * 32;
  const int x7 = lid & 7;  // XOR swizzle key (row&7 == lid&7 for all reads)

  const unsigned short* Kg = Kp + (size_t)(b * 2048) * 1024 + h * 64;
  const unsigned short* Vg = Vt + (size_t)bh * 64 * 2048;
  const float* mg = mbias + b * 2048;

  // Q fragments (B-operand of S^T): lane holds Q[q=qt*16+lid][d=ks*32+lg*8..]
  bf16x8 qf[2][2];
#pragma unroll
  for (int qt = 0; qt < 2; qt++)
#pragma unroll
    for (int ks = 0; ks < 2; ks++) {
      int qrow = b * 2048 + q0 + wq + qt * 16 + lid;
      qf[qt][ks] = *(const bf16x8*)(Qp + (size_t)qrow * 1024 + h * 64 + ks * 32 + lg * 8);
    }

  f32x4 Ot[4][2];  // O^T[d=dt*16+lg*4+r][q=qt*16+lid]
#pragma unroll
  for (int dt = 0; dt < 4; dt++)
#pragma unroll
    for (int qt = 0; qt < 2; qt++) Ot[dt][qt] = (f32x4){0.f, 0.f, 0.f, 0.f};
  f32x4 acc_l[2] = {(f32x4){0.f, 0.f, 0.f, 0.f}, (f32x4){0.f, 0.f, 0.f, 0.f}};
  bf16x8 ones8;
#pragma unroll
  for (int i = 0; i < 8; i++) ones8[i] = (__bf16)1.0f;

  // stage one 64-key tile (K 64x64, V^T 64x64) into the given buffer
  auto stage_kv = [&](unsigned short* Kl, unsigned short* Vl, int k0) {
#pragma unroll
    for (int i = 0; i < 2; i++) {
      int c = i * 256 + tid, r = c >> 3, gsw = (c & 7) ^ (r & 7);
      gload16(Kg + (size_t)(k0 + r) * 1024 + gsw * 8, Kl + c * 8);
    }
#pragma unroll
    for (int i = 0; i < 2; i++) {
      int c = i * 256 + tid, d = c >> 3, gsw = (c & 7) ^ (d & 7);
      gload16(Vg + (size_t)d * 2048 + k0 + gsw * 8, Vl + c * 8);
    }
  };

  // QK^T for one q-half; C-init = mask bias from the global table (L2-hit).
  auto qk_half = [&](int kt, const unsigned short* Kl, int qt, f32x4 (&accS)[4]) {
    const float* mrow = mg + kt * 64;
#pragma unroll
    for (int mt = 0; mt < 4; mt++)
      accS[mt] = *(const f32x4*)(&mrow[mt * 16 + lg * 4]);
    __builtin_amdgcn_s_setprio(1);
#pragma unroll
    for (int ks = 0; ks < 2; ks++) {
      int koff = ((ks * 4 + lg) ^ x7) * 8;  // swizzled granule within row
#pragma unroll
      for (int mt = 0; mt < 4; mt++) {
        bf16x8 a = *(const bf16x8*)(&Kl[(mt * 16 + lid) * 64 + koff]);
        accS[mt] = MFMA16(a, qf[qt][ks], accS[mt]);
      }
    }
    __builtin_amdgcn_s_setprio(0);
  };

  // fixed-max softmax for one q-half: p = exp2(score) -> B-frags pb[c]
  auto sm_half = [&](f32x4 (&accS)[4], bf16x8 (&pb)[2]) {
#pragma unroll
    for (int mt = 0; mt < 4; mt++) {
      int half = (mt & 1) * 4;
#pragma unroll
      for (int r = 0; r < 4; r++) {
        float p = __builtin_amdgcn_exp2f(accS[mt][r]);
        pb[mt >> 1][half + r] = (__bf16)p;
      }
    }
  };

  // PV + ones-rowsum, both q-halves (shares the V fragment loads).
  auto pv_joint = [&](bf16x8 (&pb0)[2], bf16x8 (&pb1)[2], const unsigned short* Vl) {
    __builtin_amdgcn_s_setprio(1);
#pragma unroll
    for (int c = 0; c < 2; c++) {
      acc_l[0] = MFMA16(ones8, pb0[c], acc_l[0]);
      acc_l[1] = MFMA16(ones8, pb1[c], acc_l[1]);
    }
    // O^T += V^T . P^T; phys k=lg*8+j <-> key 32*c+16*(j>=4)+lg*4+(j&3)
#pragma unroll
    for (int c = 0; c < 2; c++) {
      int glo = ((4 * c + (lg >> 1)) ^ x7) * 8 + (lg & 1) * 4;
      int ghi = ((4 * c + 2 + (lg >> 1)) ^ x7) * 8 + (lg & 1) * 4;
#pragma unroll
      for (int dt = 0; dt < 4; dt++) {
        const unsigned short* vrow = &Vl[(dt * 16 + lid) * 64];
        bf16x4 lo = *(const bf16x4*)(&vrow[glo]);
        bf16x4 hi = *(const bf16x4*)(&vrow[ghi]);
        bf16x8 av = __builtin_shufflevector(lo, hi, 0, 1, 2, 3, 4, 5, 6, 7);
        Ot[dt][0] = MFMA16(av, pb0[c], Ot[dt][0]);
        Ot[dt][1] = MFMA16(av, pb1[c], Ot[dt][1]);
      }
    }
    __builtin_amdgcn_s_setprio(0);
  };

  // one 64-key tile: q-half-split pipeline. qk(qt1) MFMAs are independent
  // of sm(qt0)'s exp chain; pv's qt0 MFMAs independent of sm(qt1) -> the
  // scheduler interleaves matrix and VALU pipes within this wave.
  auto compute_tile = [&](const unsigned short* Kl, const unsigned short* Vl, int kt) {
    f32x4 accS[4];
    bf16x8 pb0[2], pb1[2];
    qk_half(kt, Kl, 0, accS);
    sm_half(accS, pb0);
    qk_half(kt, Kl, 1, accS);
    sm_half(accS, pb1);
    pv_joint(pb0, pb1, Vl);
  };

  stage_kv(&Klds[0][0], &Vlds[0][0], 0);
  __syncthreads();  // drains vmcnt(0): buf0 ready

  // x2-unrolled: buffer bases compile-time; prefetch issued BEFORE compute,
  // drained by the end-of-tile barrier (implicit vmcnt(0)+lgkmcnt(0)).
  for (int kt = 0; kt < 32; kt += 2) {
    stage_kv(&Klds[1][0], &Vlds[1][0], (kt + 1) * 64);
    compute_tile(&Klds[0][0], &Vlds[0][0], kt);
    __syncthreads();
    if (kt + 2 < 32) stage_kv(&Klds[0][0], &Vlds[0][0], (kt + 2) * 64);
    compute_tile(&Klds[1][0], &Vlds[1][0], kt + 1);
    __syncthreads();
  }

  // epilogue: ctx[q][h*64+d] = O^T/l ; d packed x4 -> 8B stores
#pragma unroll
  for (int qt = 0; qt < 2; qt++) {
    float inv = 1.0f / acc_l[qt][0];
    int qrow = b * 2048 + q0 + wq + qt * 16 + lid;
#pragma unroll
    for (int dt = 0; dt < 4; dt++) {
      ushort4 st;
      st.x = f2bf(Ot[dt][qt][0] * inv);
      st.y = f2bf(Ot[dt][qt][1] * inv);
      st.z = f2bf(Ot[dt][qt][2] * inv);
      st.w = f2bf(Ot[dt][qt][3] * inv);
      *(ushort4*)(&ctx[(size_t)qrow * 1024 + h * 64 + dt * 16 + lg * 4]) = st;
    }
  }
}

// ---------------------------------------------------------------------------
extern "C" void kernel_launch(void* const* d_in, const int* in_sizes, int n_in,
                              void* d_out, int out_size, void* d_ws, size_t ws_size,
                              hipStream_t stream) {
  const float* q  = (const float*)d_in[0];
  const float* k  = (const float*)d_in[1];
  const float* v  = (const float*)d_in[2];
  const int*   mk = (const int*)d_in[3];
  const float* Wq = (const float*)d_in[4];
  const float* bq = (const float*)d_in[5];
  const float* Wk = (const float*)d_in[6];
  const float* bk = (const float*)d_in[7];
  const float* Wv = (const float*)d_in[8];
  const float* bv = (const float*)d_in[9];
  const float* Wo = (const float*)d_in[10];
  const float* bo = (const float*)d_in[11];

  const size_t NTOK = (size_t)8192 * 1024;   // elements per activation tensor
  const size_t NW = (size_t)1024 * 1024;     // elements per weight

  unsigned short* qb  = (unsigned short*)d_ws;
  unsigned short* kb  = qb + NTOK;
  unsigned short* vb  = kb + NTOK;
  unsigned short* Qp  = vb + NTOK;
  unsigned short* Kp  = Qp + NTOK;
  unsigned short* Vt  = Kp + NTOK;
  unsigned short* Wqb = Vt + NTOK;
  unsigned short* Wkb = Wqb + NW;
  unsigned short* Wvb = Wkb + NW;
  unsigned short* Wob = Wvb + NW;
  float*          mbg = (float*)(Wob + NW);  // (B,2048) f32 bias table, 32KB
  unsigned short* ctx = qb;  // qb dead after QKV projections

  CvtJobs J;
  J.j[0] = {q, qb, (int)(NTOK / 8)};
  J.j[1] = {k, kb, (int)(NTOK / 8)};
  J.j[2] = {v, vb, (int)(NTOK / 8)};
  J.j[3] = {Wq, Wqb, (int)(NW / 8)};
  J.j[4] = {Wk, Wkb, (int)(NW / 8)};
  J.j[5] = {Wv, Wvb, (int)(NW / 8)};
  J.j[6] = {Wo, Wob, (int)(NW / 8)};
  J.j[7] = {(const float*)mk, (unsigned short*)mbg, 2048};  // mask -> bias
  cvt_all<<<dim3(4096, 8), 256, 0, stream>>>(J);

  ProjJobs P;
  P.j[0] = {qb, Wqb, bq, Qp, SCALE_Q};
  P.j[1] = {kb, Wkb, bk, Kp, 1.0f};
  P.j[2] = {vb, Wvb, bv, Vt, 1.0f};
  gemm_qkv<<<dim3(8, 64, 3), 256, 0, stream>>>(P);

  attn<<<dim3(16, 64), 256, 0, stream>>>(Qp, Kp, Vt, mbg, ctx);
  gemm_o<<<dim3(8, 64), 256, 0, stream>>>(ctx, Wob, bo, (float*)d_out);
}

// Round 9
// 336.011 us; speedup vs baseline: 1.4935x; 1.0078x over previous
//
#include <hip/hip_runtime.h>

// ---------------------------------------------------------------------------
// MultiHeadAttention: B=4, S=2048, D=1024, H=16, Dh=64. FP32 I/O.
// cvt-all-to-bf16 (+mask->bias table) -> merged QKV GEMM (XCD-swizzled,
// single-barrier dbuf; V written in PV-fragment-permuted key layout) ->
// flash attention (fixed-max softmax; shared-K full-tile compute; all-b128
// LDS reads; 64-key dbuf; XCD-sharded) -> out GEMM (f32 out).
// ---------------------------------------------------------------------------

typedef __bf16 bf16x8 __attribute__((ext_vector_type(8)));
typedef __bf16 bf16x4 __attribute__((ext_vector_type(4)));
typedef float  f32x4  __attribute__((ext_vector_type(4)));

#define LOG2E 1.44269504088896340736f
#define SCALE_Q (0.125f * LOG2E)      // 1/sqrt(64) * log2(e), folded into Q
#define MBIAS_L2 (-1.44269504e9f)     // -1e9 * log2(e)
#define MFMA16(a, b, c) __builtin_amdgcn_mfma_f32_16x16x32_bf16(a, b, c, 0, 0, 0)

__device__ inline unsigned short f2bf(float f) {  // RNE f32 -> bf16 bits
  unsigned int u = __float_as_uint(f);
  u = u + 0x7FFF + ((u >> 16) & 1);
  return (unsigned short)(u >> 16);
}
__device__ inline void gload16(const void* g, void* l) {  // 16B global->LDS DMA
  __builtin_amdgcn_global_load_lds(
      (const __attribute__((address_space(1))) void*)g,
      (__attribute__((address_space(3))) void*)l, 16, 0, 0);
}
__device__ inline bf16x8 cvt8(const float* p) {  // 8 f32 -> bf16x8
  float4 a = *(const float4*)p, b = *(const float4*)(p + 4);
  bf16x8 v;
  v[0] = (__bf16)a.x; v[1] = (__bf16)a.y; v[2] = (__bf16)a.z; v[3] = (__bf16)a.w;
  v[4] = (__bf16)b.x; v[5] = (__bf16)b.y; v[6] = (__bf16)b.z; v[7] = (__bf16)b.w;
  return v;
}

// ---------------------------------------------------------------------------
// cvt_all: f32 -> bf16, 7 jobs (q,k,v,Wq,Wk,Wv,Wo) + job 7: mask int ->
// f32 bias table (0 / -1e9*log2e). grid (4096, 8), 256 thr.
// ---------------------------------------------------------------------------
struct CvtJob { const float* s; unsigned short* d; int n8; };
struct CvtJobs { CvtJob j[8]; };
__global__ void cvt_all(CvtJobs J) {
  CvtJob jb = J.j[blockIdx.y];
  int i = blockIdx.x * 256 + threadIdx.x;
  if (blockIdx.y == 7) {  // mask -> bias (8192 ints, int4/thread)
    if (i < jb.n8) {
      int4 m = ((const int4*)jb.s)[i];
      float4 o;
      o.x = m.x ? 0.f : MBIAS_L2;
      o.y = m.y ? 0.f : MBIAS_L2;
      o.z = m.z ? 0.f : MBIAS_L2;
      o.w = m.w ? 0.f : MBIAS_L2;
      ((float4*)jb.d)[i] = o;
    }
    return;
  }
  if (i < jb.n8) *(bf16x8*)(jb.d + (size_t)i * 8) = cvt8(jb.s + (size_t)i * 8);
}

// ---------------------------------------------------------------------------
// gemm_qkv: merged Q/K/V projections, one dispatch, grid (8, 64, 3).
// z in {0:Q, 1:K} swapped orientation (token-packed col-major stores);
// z==2 (V) normal orientation, writes Vt[(b*16+h)*64+d][perm(s)]: within
// each 32-key block, key k stored at ((k&15)>>2)*8 + ((k>>4)&1)*4 + (k&3)
// so attn's PV A-fragment (keys {32c+lg*4+0..3, 32c+16+lg*4+0..3}) is one
// contiguous 16B granule -> single ds_read_b128 (was 2x ds_read_b64).
// XCD swizzle (R7-verified) + single-barrier dbuf (R8).
// ---------------------------------------------------------------------------
struct ProjJob { const unsigned short* A; const unsigned short* W;
                 const float* bias; unsigned short* out; float scale; };
struct ProjJobs { ProjJob j[3]; };

__global__ __launch_bounds__(256, 2) void gemm_qkv(ProjJobs J) {
  __shared__ __align__(16) unsigned short Al[2][128 * 32];
  __shared__ __align__(16) unsigned short Wl[2][128 * 32];
  const int z = blockIdx.z;
  const ProjJob jb = J.j[z];
  const int tid = threadIdx.x, lane = tid & 63, w = tid >> 6;
  const int lid = lane & 15, lg = lane >> 4;
  // XCD swizzle: bijective over 512 blocks/z; z*512 preserves wg&7.
  const int lin = blockIdx.x + 8 * (int)blockIdx.y;
  const int xcd = lin & 7, j = lin >> 3;
  const int c0 = (j & 7) * 128;
  const int t0 = ((j >> 3) * 8 + xcd) * 128;
  const int wm = (w & 1) * 64, wn = (w >> 1) * 64;

  f32x4 acc[4][4];
#pragma unroll
  for (int i = 0; i < 4; i++)
#pragma unroll
    for (int jj = 0; jj < 4; jj++) acc[i][jj] = (f32x4){0.f, 0.f, 0.f, 0.f};

  auto stage = [&](int bi, int kt) {
#pragma unroll
    for (int i = 0; i < 2; i++) {
      int c = i * 256 + tid, r = c >> 2, ko = (c & 3) * 8;
      gload16(jb.A + (size_t)(t0 + r) * 1024 + kt + ko, &Al[bi][c * 8]);
      gload16(jb.W + (size_t)(c0 + r) * 1024 + kt + ko, &Wl[bi][c * 8]);
    }
  };
  auto compute = [&](int bi) {
    const unsigned short* Ml = (z == 2) ? Al[bi] : Wl[bi];
    const unsigned short* Nl = (z == 2) ? Wl[bi] : Al[bi];
    bf16x8 mf[4], nf[4];
#pragma unroll
    for (int mi = 0; mi < 4; mi++)
      mf[mi] = *(const bf16x8*)(&Ml[(wm + mi * 16 + lid) * 32 + lg * 8]);
#pragma unroll
    for (int ni = 0; ni < 4; ni++)
      nf[ni] = *(const bf16x8*)(&Nl[(wn + ni * 16 + lid) * 32 + lg * 8]);
#pragma unroll
    for (int mi = 0; mi < 4; mi++)
#pragma unroll
      for (int ni = 0; ni < 4; ni++)
        acc[mi][ni] = MFMA16(mf[mi], nf[ni], acc[mi][ni]);
  };

  stage(0, 0);
  __syncthreads();
  for (int kt = 0; kt < 1024; kt += 64) {
    stage(1, kt + 32);
    compute(0);
    __syncthreads();
    if (kt + 64 < 1024) stage(0, kt + 64);
    compute(1);
    __syncthreads();
  }

  if (z < 2) {
    const float scale = jb.scale;
#pragma unroll
    for (int mi = 0; mi < 4; mi++) {
      int colb = c0 + wm + mi * 16 + lg * 4;
      float4 b4 = *(const float4*)(&jb.bias[colb]);
#pragma unroll
      for (int ni = 0; ni < 4; ni++) {
        int token = t0 + wn + ni * 16 + lid;
        ushort4 st;
        st.x = f2bf((acc[mi][ni][0] + b4.x) * scale);
        st.y = f2bf((acc[mi][ni][1] + b4.y) * scale);
        st.z = f2bf((acc[mi][ni][2] + b4.z) * scale);
        st.w = f2bf((acc[mi][ni][3] + b4.w) * scale);
        *(ushort4*)(&jb.out[(size_t)token * 1024 + colb]) = st;
      }
    }
  } else {
    const int b = t0 >> 11;  // whole 128-token tile lies in one batch
#pragma unroll
    for (int ni = 0; ni < 4; ni++) {
      int col = c0 + wn + ni * 16 + lid;
      int h = col >> 6, d = col & 63;
      float bv = jb.bias[col];
#pragma unroll
      for (int mi = 0; mi < 4; mi++) {
        int s = (t0 & 2047) + wm + mi * 16 + lg * 4;  // 4-aligned key group
        // permuted key position (bijective per 32-block; group perm 0,2,4,6,1,3,5,7)
        int sp = (s & ~31) | (((s >> 2) & 3) << 3) | (((s >> 4) & 1) << 2);
        ushort4 st;
        st.x = f2bf(acc[mi][ni][0] + bv);
        st.y = f2bf(acc[mi][ni][1] + bv);
        st.z = f2bf(acc[mi][ni][2] + bv);
        st.w = f2bf(acc[mi][ni][3] + bv);
        *(ushort4*)(&jb.out[(size_t)((b * 16 + h) * 64 + d) * 2048 + sp]) = st;
      }
    }
  }
}

// ---------------------------------------------------------------------------
// gemm_o: f32 C[token][col] = A_bf16 @ W_bf16^T + bias. grid (8, 64).
// Same XCD swizzle + single-barrier dbuf as gemm_qkv.
// ---------------------------------------------------------------------------
__global__ __launch_bounds__(256, 2) void gemm_o(
    const unsigned short* __restrict__ A, const unsigned short* __restrict__ W,
    const float* __restrict__ bias, float* __restrict__ C) {
  __shared__ __align__(16) unsigned short Al[2][128 * 32];
  __shared__ __align__(16) unsigned short Wl[2][128 * 32];
  const int tid = threadIdx.x, lane = tid & 63, w = tid >> 6;
  const int lid = lane & 15, lg = lane >> 4;
  const int lin = blockIdx.x + 8 * (int)blockIdx.y;
  const int xcd = lin & 7, j = lin >> 3;
  const int c0 = (j & 7) * 128;
  const int t0 = ((j >> 3) * 8 + xcd) * 128;
  const int wc = (w & 1) * 64, wt = (w >> 1) * 64;
  f32x4 acc[4][4];
#pragma unroll
  for (int i = 0; i < 4; i++)
#pragma unroll
    for (int jj = 0; jj < 4; jj++) acc[i][jj] = (f32x4){0.f, 0.f, 0.f, 0.f};

  auto stage = [&](int bi, int kt) {
#pragma unroll
    for (int i = 0; i < 2; i++) {
      int c = i * 256 + tid, r = c >> 2, ko = (c & 3) * 8;
      gload16(A + (size_t)(t0 + r) * 1024 + kt + ko, &Al[bi][c * 8]);
      gload16(W + (size_t)(c0 + r) * 1024 + kt + ko, &Wl[bi][c * 8]);
    }
  };
  auto compute = [&](int bi) {
    bf16x8 aw[4], bt[4];
#pragma unroll
    for (int mi = 0; mi < 4; mi++)
      aw[mi] = *(const bf16x8*)(&Wl[bi][(wc + mi * 16 + lid) * 32 + lg * 8]);
#pragma unroll
    for (int ni = 0; ni < 4; ni++)
      bt[ni] = *(const bf16x8*)(&Al[bi][(wt + ni * 16 + lid) * 32 + lg * 8]);
#pragma unroll
    for (int mi = 0; mi < 4; mi++)
#pragma unroll
      for (int ni = 0; ni < 4; ni++)
        acc[mi][ni] = MFMA16(aw[mi], bt[ni], acc[mi][ni]);
  };

  stage(0, 0);
  __syncthreads();
  for (int kt = 0; kt < 1024; kt += 64) {
    stage(1, kt + 32);
    compute(0);
    __syncthreads();
    if (kt + 64 < 1024) stage(0, kt + 64);
    compute(1);
    __syncthreads();
  }
#pragma unroll
  for (int mi = 0; mi < 4; mi++) {
    int colb = c0 + wc + mi * 16 + lg * 4;
    float4 b4 = *(const float4*)(&bias[colb]);
#pragma unroll
    for (int ni = 0; ni < 4; ni++) {
      int token = t0 + wt + ni * 16 + lid;
      float4 st;
      st.x = acc[mi][ni][0] + b4.x;
      st.y = acc[mi][ni][1] + b4.y;
      st.z = acc[mi][ni][2] + b4.z;
      st.w = acc[mi][ni][3] + b4.w;
      *(float4*)(&C[(size_t)token * 1024 + colb]) = st;
    }
  }
}

// ---------------------------------------------------------------------------
// Flash attention v10: shared-K full-tile compute, all-b128 LDS reads.
//
// R8 LDS-pipe model: v9 read K fragments TWICE (once per q-half, 16 b128)
// and V as 16 scattered b64 -> 24KB LDS/wave/tile, the largest pipe.
// v10: (1) merge q-halves (R2's accS[4][2], fits 128-reg class: ~115 peak;
// v9 was 64 VGPR with 64 spare) -> K read once (8 b128); (2) Vt producer-
// permuted so each PV fragment is one b128 at granule (c*4+lg)^x7 -> 8
// b128. Total 16 b128 = 16KB, -33% LDS bytes, -50% LDS instructions.
// Keeps: 64-key dbuf, single barrier/tile, XCD shard, global mask table,
// ones-MFMA rowsum, (256,4). Tripwire: WRITE_SIZE 21504 (spill watch).
// ---------------------------------------------------------------------------
__global__ __launch_bounds__(256, 4) void attn(
    const unsigned short* __restrict__ Qp,   // (B*S, 1024), pre-scaled
    const unsigned short* __restrict__ Kp,   // (B*S, 1024)
    const unsigned short* __restrict__ Vt,   // (B*H, 64, 2048) key-permuted
    const float* __restrict__ mbias,         // (B, 2048) f32 bias table
    unsigned short* __restrict__ ctx) {      // (B*S, 1024)
  __shared__ __align__(16) unsigned short Klds[2][64 * 64];  // [key][d], XOR-swz
  __shared__ __align__(16) unsigned short Vlds[2][64 * 64];  // [d][key'], XOR-swz

  const int tid = threadIdx.x, lane = tid & 63, w = tid >> 6;
  const int lid = lane & 15, lg = lane >> 4;
  // XCD shard: one (b,h)'s 16 q-blocks stay on one XCD's L2.
  const int wg = blockIdx.x + (int)(gridDim.x) * blockIdx.y;
  const int xcd = wg & 7, idx = wg >> 3;
  const int bh = (xcd << 3) | (idx >> 4);
  const int q0 = (idx & 15) * 128;
  const int b = bh >> 4, h = bh & 15;
  const int wq = w * 32;
  const int x7 = lid & 7;  // XOR swizzle key (row&7 == lid&7 for all reads)

  const unsigned short* Kg = Kp + (size_t)(b * 2048) * 1024 + h * 64;
  const unsigned short* Vg = Vt + (size_t)bh * 64 * 2048;
  const float* mg = mbias + b * 2048;

  // Q fragments (B-operand of S^T): lane holds Q[q=qt*16+lid][d=ks*32+lg*8..]
  bf16x8 qf[2][2];
#pragma unroll
  for (int qt = 0; qt < 2; qt++)
#pragma unroll
    for (int ks = 0; ks < 2; ks++) {
      int qrow = b * 2048 + q0 + wq + qt * 16 + lid;
      qf[qt][ks] = *(const bf16x8*)(Qp + (size_t)qrow * 1024 + h * 64 + ks * 32 + lg * 8);
    }

  f32x4 Ot[4][2];  // O^T[d=dt*16+lg*4+r][q=qt*16+lid]
#pragma unroll
  for (int dt = 0; dt < 4; dt++)
#pragma unroll
    for (int qt = 0; qt < 2; qt++) Ot[dt][qt] = (f32x4){0.f, 0.f, 0.f, 0.f};
  f32x4 acc_l[2] = {(f32x4){0.f, 0.f, 0.f, 0.f}, (f32x4){0.f, 0.f, 0.f, 0.f}};
  bf16x8 ones8;
#pragma unroll
  for (int i = 0; i < 8; i++) ones8[i] = (__bf16)1.0f;

  // stage one 64-key tile (K 64x64, V^T 64x64) into the given buffer
  auto stage_kv = [&](unsigned short* Kl, unsigned short* Vl, int k0) {
#pragma unroll
    for (int i = 0; i < 2; i++) {
      int c = i * 256 + tid, r = c >> 3, gsw = (c & 7) ^ (r & 7);
      gload16(Kg + (size_t)(k0 + r) * 1024 + gsw * 8, Kl + c * 8);
    }
#pragma unroll
    for (int i = 0; i < 2; i++) {
      int c = i * 256 + tid, d = c >> 3, gsw = (c & 7) ^ (d & 7);
      gload16(Vg + (size_t)d * 2048 + k0 + gsw * 8, Vl + c * 8);
    }
  };

  // one 64-key tile: shared-K QK^T (both q-halves per K fragment) ->
  // softmax -> ones-rowsum + PV (single-b128 V fragments).
  auto compute_tile = [&](const unsigned short* Kl, const unsigned short* Vl, int kt) {
    const float* mrow = mg + kt * 64;
    f32x4 accS[4][2];
#pragma unroll
    for (int mt = 0; mt < 4; mt++) {
      f32x4 mb4 = *(const f32x4*)(&mrow[mt * 16 + lg * 4]);
      accS[mt][0] = mb4;
      accS[mt][1] = mb4;
    }
    __builtin_amdgcn_s_setprio(1);
#pragma unroll
    for (int ks = 0; ks < 2; ks++) {
      int koff = ((ks * 4 + lg) ^ x7) * 8;  // swizzled granule within row
#pragma unroll
      for (int mt = 0; mt < 4; mt++) {
        bf16x8 a = *(const bf16x8*)(&Kl[(mt * 16 + lid) * 64 + koff]);
        accS[mt][0] = MFMA16(a, qf[0][ks], accS[mt][0]);
        accS[mt][1] = MFMA16(a, qf[1][ks], accS[mt][1]);
      }
    }
    __builtin_amdgcn_s_setprio(0);

    // fixed-max softmax: p = exp2(score); P packed into B-frags pb[c][qt]
    bf16x8 pb[2][2];
#pragma unroll
    for (int qt = 0; qt < 2; qt++)
#pragma unroll
      for (int mt = 0; mt < 4; mt++) {
        int half = (mt & 1) * 4;
#pragma unroll
        for (int r = 0; r < 4; r++) {
          float p = __builtin_amdgcn_exp2f(accS[mt][qt][r]);
          pb[mt >> 1][qt][half + r] = (__bf16)p;
        }
      }

    __builtin_amdgcn_s_setprio(1);
    // row-sum l += ones . P^T (key permutation irrelevant for a sum)
#pragma unroll
    for (int c = 0; c < 2; c++)
#pragma unroll
      for (int qt = 0; qt < 2; qt++)
        acc_l[qt] = MFMA16(ones8, pb[c][qt], acc_l[qt]);

    // O^T += V^T . P^T; producer-permuted V: lane's 8-key fragment for
    // (c) is the single granule (c*4+lg) (swizzled), matching
    // phys k=lg*8+j <-> key 32*c+16*(j>=4)+lg*4+(j&3).
#pragma unroll
    for (int c = 0; c < 2; c++) {
      int goff = (((c * 4 + lg) ^ x7)) * 8;
#pragma unroll
      for (int dt = 0; dt < 4; dt++) {
        bf16x8 av = *(const bf16x8*)(&Vl[(dt * 16 + lid) * 64 + goff]);
        Ot[dt][0] = MFMA16(av, pb[c][0], Ot[dt][0]);
        Ot[dt][1] = MFMA16(av, pb[c][1], Ot[dt][1]);
      }
    }
    __builtin_amdgcn_s_setprio(0);
  };

  stage_kv(&Klds[0][0], &Vlds[0][0], 0);
  __syncthreads();  // drains vmcnt(0): buf0 ready

  // x2-unrolled: prefetch issued BEFORE compute, drained by the
  // end-of-tile barrier (implicit vmcnt(0)+lgkmcnt(0)).
  for (int kt = 0; kt < 32; kt += 2) {
    stage_kv(&Klds[1][0], &Vlds[1][0], (kt + 1) * 64);
    compute_tile(&Klds[0][0], &Vlds[0][0], kt);
    __syncthreads();
    if (kt + 2 < 32) stage_kv(&Klds[0][0], &Vlds[0][0], (kt + 2) * 64);
    compute_tile(&Klds[1][0], &Vlds[1][0], kt + 1);
    __syncthreads();
  }

  // epilogue: ctx[q][h*64+d] = O^T/l ; d packed x4 -> 8B stores
#pragma unroll
  for (int qt = 0; qt < 2; qt++) {
    float inv = 1.0f / acc_l[qt][0];
    int qrow = b * 2048 + q0 + wq + qt * 16 + lid;
#pragma unroll
    for (int dt = 0; dt < 4; dt++) {
      ushort4 st;
      st.x = f2bf(Ot[dt][qt][0] * inv);
      st.y = f2bf(Ot[dt][qt][1] * inv);
      st.z = f2bf(Ot[dt][qt][2] * inv);
      st.w = f2bf(Ot[dt][qt][3] * inv);
      *(ushort4*)(&ctx[(size_t)qrow * 1024 + h * 64 + dt * 16 + lg * 4]) = st;
    }
  }
}

// ---------------------------------------------------------------------------
extern "C" void kernel_launch(void* const* d_in, const int* in_sizes, int n_in,
                              void* d_out, int out_size, void* d_ws, size_t ws_size,
                              hipStream_t stream) {
  const float* q  = (const float*)d_in[0];
  const float* k  = (const float*)d_in[1];
  const float* v  = (const float*)d_in[2];
  const int*   mk = (const int*)d_in[3];
  const float* Wq = (const float*)d_in[4];
  const float* bq = (const float*)d_in[5];
  const float* Wk = (const float*)d_in[6];
  const float* bk = (const float*)d_in[7];
  const float* Wv = (const float*)d_in[8];
  const float* bv = (const float*)d_in[9];
  const float* Wo = (const float*)d_in[10];
  const float* bo = (const float*)d_in[11];

  const size_t NTOK = (size_t)8192 * 1024;   // elements per activation tensor
  const size_t NW = (size_t)1024 * 1024;     // elements per weight

  unsigned short* qb  = (unsigned short*)d_ws;
  unsigned short* kb  = qb + NTOK;
  unsigned short* vb  = kb + NTOK;
  unsigned short* Qp  = vb + NTOK;
  unsigned short* Kp  = Qp + NTOK;
  unsigned short* Vt  = Kp + NTOK;
  unsigned short* Wqb = Vt + NTOK;
  unsigned short* Wkb = Wqb + NW;
  unsigned short* Wvb = Wkb + NW;
  unsigned short* Wob = Wvb + NW;
  float*          mbg = (float*)(Wob + NW);  // (B,2048) f32 bias table, 32KB
  unsigned short* ctx = qb;  // qb dead after QKV projections

  CvtJobs J;
  J.j[0] = {q, qb, (int)(NTOK / 8)};
  J.j[1] = {k, kb, (int)(NTOK / 8)};
  J.j[2] = {v, vb, (int)(NTOK / 8)};
  J.j[3] = {Wq, Wqb, (int)(NW / 8)};
  J.j[4] = {Wk, Wkb, (int)(NW / 8)};
  J.j[5] = {Wv, Wvb, (int)(NW / 8)};
  J.j[6] = {Wo, Wob, (int)(NW / 8)};
  J.j[7] = {(const float*)mk, (unsigned short*)mbg, 2048};  // mask -> bias
  cvt_all<<<dim3(4096, 8), 256, 0, stream>>>(J);

  ProjJobs P;
  P.j[0] = {qb, Wqb, bq, Qp, SCALE_Q};
  P.j[1] = {kb, Wkb, bk, Kp, 1.0f};
  P.j[2] = {vb, Wvb, bv, Vt, 1.0f};
  gemm_qkv<<<dim3(8, 64, 3), 256, 0, stream>>>(P);

  attn<<<dim3(16, 64), 256, 0, stream>>>(Qp, Kp, Vt, mbg, ctx);
  gemm_o<<<dim3(8, 64), 256, 0, stream>>>(ctx, Wob, bo, (float*)d_out);
}

// Round 10
// 333.798 us; speedup vs baseline: 1.5034x; 1.0066x over previous
//
#include <hip/hip_runtime.h>

// ---------------------------------------------------------------------------
// MultiHeadAttention: B=4, S=2048, D=1024, H=16, Dh=64. FP32 I/O.
// cvt-all-to-bf16 (+mask->bias table) -> merged QKV GEMM (XCD-swizzled,
// dbuf, 3 blk/CU) -> flash attention (fixed-max softmax; shared-K; all-b128
// LDS; 64-key dbuf; XCD-sharded) -> out GEMM (64x128 tiles, 4 blk/CU).
// ---------------------------------------------------------------------------

typedef __bf16 bf16x8 __attribute__((ext_vector_type(8)));
typedef __bf16 bf16x4 __attribute__((ext_vector_type(4)));
typedef float  f32x4  __attribute__((ext_vector_type(4)));

#define LOG2E 1.44269504088896340736f
#define SCALE_Q (0.125f * LOG2E)      // 1/sqrt(64) * log2(e), folded into Q
#define MBIAS_L2 (-1.44269504e9f)     // -1e9 * log2(e)
#define MFMA16(a, b, c) __builtin_amdgcn_mfma_f32_16x16x32_bf16(a, b, c, 0, 0, 0)

__device__ inline unsigned short f2bf(float f) {  // RNE f32 -> bf16 bits
  unsigned int u = __float_as_uint(f);
  u = u + 0x7FFF + ((u >> 16) & 1);
  return (unsigned short)(u >> 16);
}
__device__ inline void gload16(const void* g, void* l) {  // 16B global->LDS DMA
  __builtin_amdgcn_global_load_lds(
      (const __attribute__((address_space(1))) void*)g,
      (__attribute__((address_space(3))) void*)l, 16, 0, 0);
}
__device__ inline bf16x8 cvt8(const float* p) {  // 8 f32 -> bf16x8
  float4 a = *(const float4*)p, b = *(const float4*)(p + 4);
  bf16x8 v;
  v[0] = (__bf16)a.x; v[1] = (__bf16)a.y; v[2] = (__bf16)a.z; v[3] = (__bf16)a.w;
  v[4] = (__bf16)b.x; v[5] = (__bf16)b.y; v[6] = (__bf16)b.z; v[7] = (__bf16)b.w;
  return v;
}

// ---------------------------------------------------------------------------
// cvt_all: f32 -> bf16, 7 jobs (q,k,v,Wq,Wk,Wv,Wo) + job 7: mask int ->
// f32 bias table (0 / -1e9*log2e). grid (4096, 8), 256 thr.
// ---------------------------------------------------------------------------
struct CvtJob { const float* s; unsigned short* d; int n8; };
struct CvtJobs { CvtJob j[8]; };
__global__ void cvt_all(CvtJobs J) {
  CvtJob jb = J.j[blockIdx.y];
  int i = blockIdx.x * 256 + threadIdx.x;
  if (blockIdx.y == 7) {  // mask -> bias (8192 ints, int4/thread)
    if (i < jb.n8) {
      int4 m = ((const int4*)jb.s)[i];
      float4 o;
      o.x = m.x ? 0.f : MBIAS_L2;
      o.y = m.y ? 0.f : MBIAS_L2;
      o.z = m.z ? 0.f : MBIAS_L2;
      o.w = m.w ? 0.f : MBIAS_L2;
      ((float4*)jb.d)[i] = o;
    }
    return;
  }
  if (i < jb.n8) *(bf16x8*)(jb.d + (size_t)i * 8) = cvt8(jb.s + (size_t)i * 8);
}

// ---------------------------------------------------------------------------
// gemm_qkv: merged Q/K/V projections, one dispatch, grid (8, 64, 3).
// z in {0:Q, 1:K} swapped orientation (token-packed col-major stores);
// z==2 (V) normal orientation, writes Vt[(b*16+h)*64+d][perm(s)]: within
// each 32-key block, key k stored at ((k&15)>>2)*8 + ((k>>4)&1)*4 + (k&3)
// so attn's PV A-fragment is one contiguous b128 granule.
// XCD swizzle (R7) + single-barrier dbuf (R8). R10: launch_bounds (256,3)
// -> 3 blocks/CU resident (was 2; grid offers 6/CU; 124 combined regs fit
// the ~170-reg class with margin - no spill risk).
// ---------------------------------------------------------------------------
struct ProjJob { const unsigned short* A; const unsigned short* W;
                 const float* bias; unsigned short* out; float scale; };
struct ProjJobs { ProjJob j[3]; };

__global__ __launch_bounds__(256, 3) void gemm_qkv(ProjJobs J) {
  __shared__ __align__(16) unsigned short Al[2][128 * 32];
  __shared__ __align__(16) unsigned short Wl[2][128 * 32];
  const int z = blockIdx.z;
  const ProjJob jb = J.j[z];
  const int tid = threadIdx.x, lane = tid & 63, w = tid >> 6;
  const int lid = lane & 15, lg = lane >> 4;
  // XCD swizzle: bijective over 512 blocks/z; z*512 preserves wg&7.
  const int lin = blockIdx.x + 8 * (int)blockIdx.y;
  const int xcd = lin & 7, j = lin >> 3;
  const int c0 = (j & 7) * 128;
  const int t0 = ((j >> 3) * 8 + xcd) * 128;
  const int wm = (w & 1) * 64, wn = (w >> 1) * 64;

  f32x4 acc[4][4];
#pragma unroll
  for (int i = 0; i < 4; i++)
#pragma unroll
    for (int jj = 0; jj < 4; jj++) acc[i][jj] = (f32x4){0.f, 0.f, 0.f, 0.f};

  auto stage = [&](int bi, int kt) {
#pragma unroll
    for (int i = 0; i < 2; i++) {
      int c = i * 256 + tid, r = c >> 2, ko = (c & 3) * 8;
      gload16(jb.A + (size_t)(t0 + r) * 1024 + kt + ko, &Al[bi][c * 8]);
      gload16(jb.W + (size_t)(c0 + r) * 1024 + kt + ko, &Wl[bi][c * 8]);
    }
  };
  auto compute = [&](int bi) {
    const unsigned short* Ml = (z == 2) ? Al[bi] : Wl[bi];
    const unsigned short* Nl = (z == 2) ? Wl[bi] : Al[bi];
    bf16x8 mf[4], nf[4];
#pragma unroll
    for (int mi = 0; mi < 4; mi++)
      mf[mi] = *(const bf16x8*)(&Ml[(wm + mi * 16 + lid) * 32 + lg * 8]);
#pragma unroll
    for (int ni = 0; ni < 4; ni++)
      nf[ni] = *(const bf16x8*)(&Nl[(wn + ni * 16 + lid) * 32 + lg * 8]);
#pragma unroll
    for (int mi = 0; mi < 4; mi++)
#pragma unroll
      for (int ni = 0; ni < 4; ni++)
        acc[mi][ni] = MFMA16(mf[mi], nf[ni], acc[mi][ni]);
  };

  stage(0, 0);
  __syncthreads();
  for (int kt = 0; kt < 1024; kt += 64) {
    stage(1, kt + 32);
    compute(0);
    __syncthreads();
    if (kt + 64 < 1024) stage(0, kt + 64);
    compute(1);
    __syncthreads();
  }

  if (z < 2) {
    const float scale = jb.scale;
#pragma unroll
    for (int mi = 0; mi < 4; mi++) {
      int colb = c0 + wm + mi * 16 + lg * 4;
      float4 b4 = *(const float4*)(&jb.bias[colb]);
#pragma unroll
      for (int ni = 0; ni < 4; ni++) {
        int token = t0 + wn + ni * 16 + lid;
        ushort4 st;
        st.x = f2bf((acc[mi][ni][0] + b4.x) * scale);
        st.y = f2bf((acc[mi][ni][1] + b4.y) * scale);
        st.z = f2bf((acc[mi][ni][2] + b4.z) * scale);
        st.w = f2bf((acc[mi][ni][3] + b4.w) * scale);
        *(ushort4*)(&jb.out[(size_t)token * 1024 + colb]) = st;
      }
    }
  } else {
    const int b = t0 >> 11;  // whole 128-token tile lies in one batch
#pragma unroll
    for (int ni = 0; ni < 4; ni++) {
      int col = c0 + wn + ni * 16 + lid;
      int h = col >> 6, d = col & 63;
      float bv = jb.bias[col];
#pragma unroll
      for (int mi = 0; mi < 4; mi++) {
        int s = (t0 & 2047) + wm + mi * 16 + lg * 4;  // 4-aligned key group
        // permuted key position (bijective per 32-block)
        int sp = (s & ~31) | (((s >> 2) & 3) << 3) | (((s >> 4) & 1) << 2);
        ushort4 st;
        st.x = f2bf(acc[mi][ni][0] + bv);
        st.y = f2bf(acc[mi][ni][1] + bv);
        st.z = f2bf(acc[mi][ni][2] + bv);
        st.w = f2bf(acc[mi][ni][3] + bv);
        *(ushort4*)(&jb.out[(size_t)((b * 16 + h) * 64 + d) * 2048 + sp]) = st;
      }
    }
  }
}

// ---------------------------------------------------------------------------
// gemm_o: f32 C[token][col] = A_bf16 @ W_bf16^T + bias.
// R10 re-tile: 64 tokens x 128 cols per block, grid (8,128) = 1024 blocks
// = 4/CU (was 128x128, 512 blocks = 2/CU, grid-capped). acc[4][2] = 32
// AGPR + ~55 VGPR fits (256,4). LDS 24KB. Same XCD swizzle (each XCD: 16
// token-panels x all 8 col-tiles -> A 2MB + W 2MB = L2) + dbuf.
// ---------------------------------------------------------------------------
__global__ __launch_bounds__(256, 4) void gemm_o(
    const unsigned short* __restrict__ A, const unsigned short* __restrict__ W,
    const float* __restrict__ bias, float* __restrict__ C) {
  __shared__ __align__(16) unsigned short Al[2][64 * 32];
  __shared__ __align__(16) unsigned short Wl[2][128 * 32];
  const int tid = threadIdx.x, lane = tid & 63, w = tid >> 6;
  const int lid = lane & 15, lg = lane >> 4;
  const int lin = blockIdx.x + 8 * (int)blockIdx.y;  // grid (8,128) = 1024
  const int xcd = lin & 7, j = lin >> 3;             // j in 0..127
  const int c0 = (j & 7) * 128;
  const int t0 = ((j >> 3) * 8 + xcd) * 64;
  const int wc = (w & 1) * 64, wt = (w >> 1) * 32;
  f32x4 acc[4][2];
#pragma unroll
  for (int i = 0; i < 4; i++)
#pragma unroll
    for (int jj = 0; jj < 2; jj++) acc[i][jj] = (f32x4){0.f, 0.f, 0.f, 0.f};

  auto stage = [&](int bi, int kt) {
#pragma unroll
    for (int i = 0; i < 2; i++) {
      int c = i * 256 + tid, r = c >> 2, ko = (c & 3) * 8;
      gload16(W + (size_t)(c0 + r) * 1024 + kt + ko, &Wl[bi][c * 8]);
    }
    {
      int c = tid, r = c >> 2, ko = (c & 3) * 8;
      gload16(A + (size_t)(t0 + r) * 1024 + kt + ko, &Al[bi][c * 8]);
    }
  };
  auto compute = [&](int bi) {
    bf16x8 aw[4], bt[2];
#pragma unroll
    for (int mi = 0; mi < 4; mi++)
      aw[mi] = *(const bf16x8*)(&Wl[bi][(wc + mi * 16 + lid) * 32 + lg * 8]);
#pragma unroll
    for (int ni = 0; ni < 2; ni++)
      bt[ni] = *(const bf16x8*)(&Al[bi][(wt + ni * 16 + lid) * 32 + lg * 8]);
#pragma unroll
    for (int mi = 0; mi < 4; mi++)
#pragma unroll
      for (int ni = 0; ni < 2; ni++)
        acc[mi][ni] = MFMA16(aw[mi], bt[ni], acc[mi][ni]);
  };

  stage(0, 0);
  __syncthreads();
  for (int kt = 0; kt < 1024; kt += 64) {
    stage(1, kt + 32);
    compute(0);
    __syncthreads();
    if (kt + 64 < 1024) stage(0, kt + 64);
    compute(1);
    __syncthreads();
  }
#pragma unroll
  for (int mi = 0; mi < 4; mi++) {
    int colb = c0 + wc + mi * 16 + lg * 4;
    float4 b4 = *(const float4*)(&bias[colb]);
#pragma unroll
    for (int ni = 0; ni < 2; ni++) {
      int token = t0 + wt + ni * 16 + lid;
      float4 st;
      st.x = acc[mi][ni][0] + b4.x;
      st.y = acc[mi][ni][1] + b4.y;
      st.z = acc[mi][ni][2] + b4.z;
      st.w = acc[mi][ni][3] + b4.w;
      *(float4*)(&C[(size_t)token * 1024 + colb]) = st;
    }
  }
}

// ---------------------------------------------------------------------------
// Flash attention v10 (unchanged from R9: 79us, 0 bank conflicts, no spill).
// ---------------------------------------------------------------------------
__global__ __launch_bounds__(256, 4) void attn(
    const unsigned short* __restrict__ Qp,   // (B*S, 1024), pre-scaled
    const unsigned short* __restrict__ Kp,   // (B*S, 1024)
    const unsigned short* __restrict__ Vt,   // (B*H, 64, 2048) key-permuted
    const float* __restrict__ mbias,         // (B, 2048) f32 bias table
    unsigned short* __restrict__ ctx) {      // (B*S, 1024)
  __shared__ __align__(16) unsigned short Klds[2][64 * 64];  // [key][d], XOR-swz
  __shared__ __align__(16) unsigned short Vlds[2][64 * 64];  // [d][key'], XOR-swz

  const int tid = threadIdx.x, lane = tid & 63, w = tid >> 6;
  const int lid = lane & 15, lg = lane >> 4;
  // XCD shard: one (b,h)'s 16 q-blocks stay on one XCD's L2.
  const int wg = blockIdx.x + (int)(gridDim.x) * blockIdx.y;
  const int xcd = wg & 7, idx = wg >> 3;
  const int bh = (xcd << 3) | (idx >> 4);
  const int q0 = (idx & 15) * 128;
  const int b = bh >> 4, h = bh & 15;
  const int wq = w * 32;
  const int x7 = lid & 7;  // XOR swizzle key (row&7 == lid&7 for all reads)

  const unsigned short* Kg = Kp + (size_t)(b * 2048) * 1024 + h * 64;
  const unsigned short* Vg = Vt + (size_t)bh * 64 * 2048;
  const float* mg = mbias + b * 2048;

  // Q fragments (B-operand of S^T): lane holds Q[q=qt*16+lid][d=ks*32+lg*8..]
  bf16x8 qf[2][2];
#pragma unroll
  for (int qt = 0; qt < 2; qt++)
#pragma unroll
    for (int ks = 0; ks < 2; ks++) {
      int qrow = b * 2048 + q0 + wq + qt * 16 + lid;
      qf[qt][ks] = *(const bf16x8*)(Qp + (size_t)qrow * 1024 + h * 64 + ks * 32 + lg * 8);
    }

  f32x4 Ot[4][2];  // O^T[d=dt*16+lg*4+r][q=qt*16+lid]
#pragma unroll
  for (int dt = 0; dt < 4; dt++)
#pragma unroll
    for (int qt = 0; qt < 2; qt++) Ot[dt][qt] = (f32x4){0.f, 0.f, 0.f, 0.f};
  f32x4 acc_l[2] = {(f32x4){0.f, 0.f, 0.f, 0.f}, (f32x4){0.f, 0.f, 0.f, 0.f}};
  bf16x8 ones8;
#pragma unroll
  for (int i = 0; i < 8; i++) ones8[i] = (__bf16)1.0f;

  // stage one 64-key tile (K 64x64, V^T 64x64) into the given buffer
  auto stage_kv = [&](unsigned short* Kl, unsigned short* Vl, int k0) {
#pragma unroll
    for (int i = 0; i < 2; i++) {
      int c = i * 256 + tid, r = c >> 3, gsw = (c & 7) ^ (r & 7);
      gload16(Kg + (size_t)(k0 + r) * 1024 + gsw * 8, Kl + c * 8);
    }
#pragma unroll
    for (int i = 0; i < 2; i++) {
      int c = i * 256 + tid, d = c >> 3, gsw = (c & 7) ^ (d & 7);
      gload16(Vg + (size_t)d * 2048 + k0 + gsw * 8, Vl + c * 8);
    }
  };

  // one 64-key tile: shared-K QK^T (both q-halves per K fragment) ->
  // softmax -> ones-rowsum + PV (single-b128 V fragments).
  auto compute_tile = [&](const unsigned short* Kl, const unsigned short* Vl, int kt) {
    const float* mrow = mg + kt * 64;
    f32x4 accS[4][2];
#pragma unroll
    for (int mt = 0; mt < 4; mt++) {
      f32x4 mb4 = *(const f32x4*)(&mrow[mt * 16 + lg * 4]);
      accS[mt][0] = mb4;
      accS[mt][1] = mb4;
    }
    __builtin_amdgcn_s_setprio(1);
#pragma unroll
    for (int ks = 0; ks < 2; ks++) {
      int koff = ((ks * 4 + lg) ^ x7) * 8;  // swizzled granule within row
#pragma unroll
      for (int mt = 0; mt < 4; mt++) {
        bf16x8 a = *(const bf16x8*)(&Kl[(mt * 16 + lid) * 64 + koff]);
        accS[mt][0] = MFMA16(a, qf[0][ks], accS[mt][0]);
        accS[mt][1] = MFMA16(a, qf[1][ks], accS[mt][1]);
      }
    }
    __builtin_amdgcn_s_setprio(0);

    // fixed-max softmax: p = exp2(score); P packed into B-frags pb[c][qt]
    bf16x8 pb[2][2];
#pragma unroll
    for (int qt = 0; qt < 2; qt++)
#pragma unroll
      for (int mt = 0; mt < 4; mt++) {
        int half = (mt & 1) * 4;
#pragma unroll
        for (int r = 0; r < 4; r++) {
          float p = __builtin_amdgcn_exp2f(accS[mt][qt][r]);
          pb[mt >> 1][qt][half + r] = (__bf16)p;
        }
      }

    __builtin_amdgcn_s_setprio(1);
    // row-sum l += ones . P^T (key permutation irrelevant for a sum)
#pragma unroll
    for (int c = 0; c < 2; c++)
#pragma unroll
      for (int qt = 0; qt < 2; qt++)
        acc_l[qt] = MFMA16(ones8, pb[c][qt], acc_l[qt]);

    // O^T += V^T . P^T; producer-permuted V: one b128 granule per (c).
#pragma unroll
    for (int c = 0; c < 2; c++) {
      int goff = (((c * 4 + lg) ^ x7)) * 8;
#pragma unroll
      for (int dt = 0; dt < 4; dt++) {
        bf16x8 av = *(const bf16x8*)(&Vl[(dt * 16 + lid) * 64 + goff]);
        Ot[dt][0] = MFMA16(av, pb[c][0], Ot[dt][0]);
        Ot[dt][1] = MFMA16(av, pb[c][1], Ot[dt][1]);
      }
    }
    __builtin_amdgcn_s_setprio(0);
  };

  stage_kv(&Klds[0][0], &Vlds[0][0], 0);
  __syncthreads();  // drains vmcnt(0): buf0 ready

  // x2-unrolled: prefetch issued BEFORE compute, drained by the
  // end-of-tile barrier (implicit vmcnt(0)+lgkmcnt(0)).
  for (int kt = 0; kt < 32; kt += 2) {
    stage_kv(&Klds[1][0], &Vlds[1][0], (kt + 1) * 64);
    compute_tile(&Klds[0][0], &Vlds[0][0], kt);
    __syncthreads();
    if (kt + 2 < 32) stage_kv(&Klds[0][0], &Vlds[0][0], (kt + 2) * 64);
    compute_tile(&Klds[1][0], &Vlds[1][0], kt + 1);
    __syncthreads();
  }

  // epilogue: ctx[q][h*64+d] = O^T/l ; d packed x4 -> 8B stores
#pragma unroll
  for (int qt = 0; qt < 2; qt++) {
    float inv = 1.0f / acc_l[qt][0];
    int qrow = b * 2048 + q0 + wq + qt * 16 + lid;
#pragma unroll
    for (int dt = 0; dt < 4; dt++) {
      ushort4 st;
      st.x = f2bf(Ot[dt][qt][0] * inv);
      st.y = f2bf(Ot[dt][qt][1] * inv);
      st.z = f2bf(Ot[dt][qt][2] * inv);
      st.w = f2bf(Ot[dt][qt][3] * inv);
      *(ushort4*)(&ctx[(size_t)qrow * 1024 + h * 64 + dt * 16 + lg * 4]) = st;
    }
  }
}

// ---------------------------------------------------------------------------
extern "C" void kernel_launch(void* const* d_in, const int* in_sizes, int n_in,
                              void* d_out, int out_size, void* d_ws, size_t ws_size,
                              hipStream_t stream) {
  const float* q  = (const float*)d_in[0];
  const float* k  = (const float*)d_in[1];
  const float* v  = (const float*)d_in[2];
  const int*   mk = (const int*)d_in[3];
  const float* Wq = (const float*)d_in[4];
  const float* bq = (const float*)d_in[5];
  const float* Wk = (const float*)d_in[6];
  const float* bk = (const float*)d_in[7];
  const float* Wv = (const float*)d_in[8];
  const float* bv = (const float*)d_in[9];
  const float* Wo = (const float*)d_in[10];
  const float* bo = (const float*)d_in[11];

  const size_t NTOK = (size_t)8192 * 1024;   // elements per activation tensor
  const size_t NW = (size_t)1024 * 1024;     // elements per weight

  unsigned short* qb  = (unsigned short*)d_ws;
  unsigned short* kb  = qb + NTOK;
  unsigned short* vb  = kb + NTOK;
  unsigned short* Qp  = vb + NTOK;
  unsigned short* Kp  = Qp + NTOK;
  unsigned short* Vt  = Kp + NTOK;
  unsigned short* Wqb = Vt + NTOK;
  unsigned short* Wkb = Wqb + NW;
  unsigned short* Wvb = Wkb + NW;
  unsigned short* Wob = Wvb + NW;
  float*          mbg = (float*)(Wob + NW);  // (B,2048) f32 bias table, 32KB
  unsigned short* ctx = qb;  // qb dead after QKV projections

  CvtJobs J;
  J.j[0] = {q, qb, (int)(NTOK / 8)};
  J.j[1] = {k, kb, (int)(NTOK / 8)};
  J.j[2] = {v, vb, (int)(NTOK / 8)};
  J.j[3] = {Wq, Wqb, (int)(NW / 8)};
  J.j[4] = {Wk, Wkb, (int)(NW / 8)};
  J.j[5] = {Wv, Wvb, (int)(NW / 8)};
  J.j[6] = {Wo, Wob, (int)(NW / 8)};
  J.j[7] = {(const float*)mk, (unsigned short*)mbg, 2048};  // mask -> bias
  cvt_all<<<dim3(4096, 8), 256, 0, stream>>>(J);

  ProjJobs P;
  P.j[0] = {qb, Wqb, bq, Qp, SCALE_Q};
  P.j[1] = {kb, Wkb, bk, Kp, 1.0f};
  P.j[2] = {vb, Wvb, bv, Vt, 1.0f};
  gemm_qkv<<<dim3(8, 64, 3), 256, 0, stream>>>(P);

  attn<<<dim3(16, 64), 256, 0, stream>>>(Qp, Kp, Vt, mbg, ctx);
  gemm_o<<<dim3(8, 128), 256, 0, stream>>>(ctx, Wob, bo, (float*)d_out);
}